// Round 1
// baseline (478.007 us; speedup 1.0000x reference)
//
#include <hip/hip_runtime.h>
#include <stdint.h>

#define NB 4
#define CC 256
#define C16 16
#define HH 64
#define WW 64
#define NN 4096

typedef __attribute__((ext_vector_type(8))) short short8;
typedef __attribute__((ext_vector_type(4))) float floatx4;

__device__ __forceinline__ unsigned short f2bf(float f) {
    union { float f; unsigned u; } v; v.f = f;
    unsigned r = v.u + 0x7fffu + ((v.u >> 16) & 1u);
    return (unsigned short)(r >> 16);
}

// ---------------- q conv (1x3, pad w) + k conv (3x1, pad h), fp32 ----------------
__global__ __launch_bounds__(512) void conv_qk_kernel(
        const float* __restrict__ x, const float* __restrict__ wq,
        const float* __restrict__ bq, const float* __restrict__ wk,
        const float* __restrict__ bk, float* __restrict__ qraw,
        float* __restrict__ kraw) {
    int b = blockIdx.x >> 6, h = blockIdx.x & 63;
    int tid = threadIdx.x;
    int w = tid & 63;
    int og = __builtin_amdgcn_readfirstlane(tid >> 6); // 0..7, wave-uniform
    int o0 = og * 2;
    const float* xb = x + ((size_t)b * CC) * NN + h * WW + w;
    float qa0 = bq[o0], qa1 = bq[o0 + 1];
    float ka0 = bk[o0], ka1 = bk[o0 + 1];
    for (int c = 0; c < CC; ++c) {
        const float* xc = xb + (size_t)c * NN;
        float x0 = xc[0];
        float xl = (w > 0)  ? xc[-1]  : 0.f;
        float xr = (w < 63) ? xc[1]   : 0.f;
        float xu = (h > 0)  ? xc[-WW] : 0.f;
        float xd = (h < 63) ? xc[WW]  : 0.f;
        const float* q0 = wq + (o0 * CC + c) * 3;
        const float* q1 = q0 + CC * 3;
        const float* k0 = wk + (o0 * CC + c) * 3;
        const float* k1 = k0 + CC * 3;
        qa0 += xl * q0[0] + x0 * q0[1] + xr * q0[2];
        qa1 += xl * q1[0] + x0 * q1[1] + xr * q1[2];
        ka0 += xu * k0[0] + x0 * k0[1] + xd * k0[2];
        ka1 += xu * k1[0] + x0 * k1[1] + xd * k1[2];
    }
    int n = h * WW + w;
    qraw[(size_t)(b * C16 + o0) * NN + n]     = qa0;
    qraw[(size_t)(b * C16 + o0 + 1) * NN + n] = qa1;
    kraw[(size_t)(b * C16 + o0) * NN + n]     = ka0;
    kraw[(size_t)(b * C16 + o0 + 1) * NN + n] = ka1;
}

// ---------------- FRN stats: nu2[b,o] = mean over N of raw^2 ----------------
__global__ __launch_bounds__(256) void frn_stats_kernel(
        const float* __restrict__ qraw, const float* __restrict__ kraw,
        float* __restrict__ nu2) {
    int blk = blockIdx.x;                 // 0..63 q, 64..127 k
    const float* src = (blk & 64) ? kraw : qraw;
    int bo = blk & 63;
    const floatx4* p = (const floatx4*)(src + (size_t)bo * NN);
    float s = 0.f;
    for (int i = 0; i < 4; ++i) {
        floatx4 v = p[threadIdx.x + 256 * i];
        s += v[0]*v[0] + v[1]*v[1] + v[2]*v[2] + v[3]*v[3];
    }
    for (int off = 1; off < 64; off <<= 1) s += __shfl_xor(s, off, 64);
    __shared__ float part[4];
    if ((threadIdx.x & 63) == 0) part[threadIdx.x >> 6] = s;
    __syncthreads();
    if (threadIdx.x == 0)
        nu2[blk] = (part[0] + part[1] + part[2] + part[3]) * (1.f / (float)NN);
}

// ---------------- FRN normalize + Mish, transpose-write bf16 [b][n][16] ----------------
__global__ __launch_bounds__(256) void frn_mish_kernel(
        const float* __restrict__ qraw, const float* __restrict__ kraw,
        const float* __restrict__ nu2, const float* __restrict__ eps_q,
        const float* __restrict__ eps_k, unsigned short* __restrict__ qb,
        unsigned short* __restrict__ kb) {
    int blk = blockIdx.x;
    int tensor = blk >> 6;
    int b = (blk >> 4) & 3;
    int ch = blk & 15;
    const float* raw = tensor ? kraw : qraw;
    const float* eps = tensor ? eps_k : eps_q;
    unsigned short* outp = tensor ? kb : qb;
    const float* nu = nu2 + tensor * 64 + b * C16;
    int n = ch * 256 + threadIdx.x;
    union { unsigned short s[16]; uint4 u[2]; } pk;
    for (int o = 0; o < C16; ++o) {
        float r = raw[(size_t)(b * C16 + o) * NN + n];
        float v = r * rsqrtf(nu[o] + fabsf(eps[o]));
        float sp = fmaxf(v, 0.f) + log1pf(expf(-fabsf(v)));   // stable softplus
        pk.s[o] = f2bf(v * tanhf(sp));
    }
    uint4* dst = (uint4*)(outp + (size_t)(b * NN + n) * C16);
    dst[0] = pk.u[0];
    dst[1] = pk.u[1];
}

// ---------------- v = 1x1 conv (256x256 GEMM), fp32 acc, bf16 out [b][c][n] ----------------
__global__ __launch_bounds__(256) void conv_v_kernel(
        const float* __restrict__ x, const float* __restrict__ wv,
        const float* __restrict__ bv, unsigned short* __restrict__ vb) {
    __shared__ float xsh[CC][64];
    int b = blockIdx.x >> 6, nt = blockIdx.x & 63;
    int n0 = nt * 64;
    int tid = threadIdx.x;
    const float* xb = x + (size_t)b * CC * NN + n0;
    for (int i = 0; i < 16; ++i) {
        int idx = tid + 256 * i;
        int ci = idx >> 4, f4 = idx & 15;
        *(float4*)&xsh[ci][f4 * 4] = *(const float4*)(xb + (size_t)ci * NN + f4 * 4);
    }
    __syncthreads();
    int n = tid & 63;
    int cg = __builtin_amdgcn_readfirstlane(tid >> 6);
    for (int cc = 0; cc < 64; cc += 8) {
        int c = cg * 64 + cc;
        float acc[8];
        for (int u = 0; u < 8; ++u) acc[u] = bv[c + u];
        for (int ci = 0; ci < CC; ++ci) {
            float xv = xsh[ci][n];
            const float* wr = wv + (size_t)c * CC + ci;
            for (int u = 0; u < 8; ++u) acc[u] = fmaf(wr[u * CC], xv, acc[u]);
        }
        for (int u = 0; u < 8; ++u)
            vb[(size_t)(b * CC + c + u) * NN + n0 + n] = f2bf(acc[u]);
    }
}

// ---------------- flash attention + epilogue gamma*W + x ----------------
// grid (64 j-tiles, B). block 256 = 4 waves. Each wave: S rows [16w,16w+16),
// PV tile 64j x 64c (c range [64w, 64w+64)).
__global__ __launch_bounds__(256) void attn_kernel(
        const unsigned short* __restrict__ qb, const unsigned short* __restrict__ kb,
        const unsigned short* __restrict__ vb, const float* __restrict__ x,
        const float* __restrict__ gamma_p, float* __restrict__ out) {
    __shared__ __align__(16) unsigned short vlds[CC][72];  // padded stride
    __shared__ __align__(16) unsigned short plds[64][72];
    __shared__ __align__(16) float alpha_sh[64];
    __shared__ __align__(16) float l_sh[64];
    __shared__ __align__(16) float obuf[4][16][67];

    int tid = threadIdx.x;
    int wv_ = __builtin_amdgcn_readfirstlane(tid >> 6);
    int lane = tid & 63;
    int q16 = lane >> 4, c16 = lane & 15;
    int b = blockIdx.y;
    int jbase = blockIdx.x * 64;

    short8 zero8 = {0, 0, 0, 0, 0, 0, 0, 0};
    floatx4 fzero = {0.f, 0.f, 0.f, 0.f};

    // Q A-frag: A[m=c16][k=q16*8+t]; d-dim 16 padded to K=32 with zeros
    short8 aq = zero8;
    if (q16 < 2)
        aq = *(const short8*)(qb + (size_t)(b * NN + jbase + wv_ * 16 + c16) * C16 + q16 * 8);

    floatx4 acc[4][4];
    for (int jt = 0; jt < 4; ++jt)
        for (int ct = 0; ct < 4; ++ct) acc[jt][ct] = fzero;
    float m_r[4] = {-INFINITY, -INFINITY, -INFINITY, -INFINITY};
    float l_r[4] = {0.f, 0.f, 0.f, 0.f};

    const unsigned short* vbb = vb + (size_t)b * CC * NN;
    const unsigned short* kbb = kb + (size_t)b * NN * C16;

    for (int it = 0; it < 64; ++it) {
        int n0 = it * 64;
        __syncthreads();   // vlds/plds/alpha_sh free to overwrite
        // stage V tile: 256c x 64n bf16
        for (int i = 0; i < 8; ++i) {
            int idx = tid + 256 * i;
            int c = idx >> 3, off = idx & 7;
            *(uint4*)&vlds[c][off * 8] = *(const uint4*)(vbb + (size_t)c * NN + n0 + off * 8);
        }
        // S = Q K^T for this wave's 16 rows; B[k=d][n]=k_t[n][d]
        floatx4 sv[4];
        for (int s = 0; s < 4; ++s) {
            short8 bk8 = zero8;
            if (q16 < 2)
                bk8 = *(const short8*)(kbb + (size_t)(n0 + s * 16 + c16) * C16 + q16 * 8);
            sv[s] = __builtin_amdgcn_mfma_f32_16x16x32_bf16(aq, bk8, fzero, 0, 0, 0);
        }
        // online softmax: C-layout row = q16*4+r, col = c16 + 16s
        float al[4];
        for (int r = 0; r < 4; ++r) {
            float mt = fmaxf(fmaxf(sv[0][r], sv[1][r]), fmaxf(sv[2][r], sv[3][r]));
            mt = fmaxf(mt, __shfl_xor(mt, 1, 64));
            mt = fmaxf(mt, __shfl_xor(mt, 2, 64));
            mt = fmaxf(mt, __shfl_xor(mt, 4, 64));
            mt = fmaxf(mt, __shfl_xor(mt, 8, 64));
            float mn = fmaxf(m_r[r], mt);
            al[r] = __expf(m_r[r] - mn);
            m_r[r] = mn;
            float lt = 0.f;
            int prow = wv_ * 16 + q16 * 4 + r;
            for (int s = 0; s < 4; ++s) {
                float pv = __expf(sv[s][r] - mn);
                lt += pv;
                plds[prow][s * 16 + c16] = f2bf(pv);
            }
            lt += __shfl_xor(lt, 1, 64);
            lt += __shfl_xor(lt, 2, 64);
            lt += __shfl_xor(lt, 4, 64);
            lt += __shfl_xor(lt, 8, 64);
            l_r[r] = l_r[r] * al[r] + lt;
        }
        if (c16 < 4) {
            float a = (c16 == 0) ? al[0] : (c16 == 1) ? al[1] : (c16 == 2) ? al[2] : al[3];
            alpha_sh[wv_ * 16 + q16 * 4 + c16] = a;
        }
        __syncthreads();   // plds + alpha_sh + vlds ready for all waves
        // rescale O (rows j-rel = jt*16 + q16*4 + r, matches alpha layout)
        for (int jt = 0; jt < 4; ++jt) {
            floatx4 a4 = *(const floatx4*)&alpha_sh[jt * 16 + q16 * 4];
            for (int ct = 0; ct < 4; ++ct) {
                acc[jt][ct][0] *= a4[0];
                acc[jt][ct][1] *= a4[1];
                acc[jt][ct][2] *= a4[2];
                acc[jt][ct][3] *= a4[3];
            }
        }
        // PV: A = P[j][n], B[k=n][c] = v[c][n]
        for (int h = 0; h < 2; ++h) {
            short8 pf[4];
            for (int jt = 0; jt < 4; ++jt)
                pf[jt] = *(const short8*)&plds[jt * 16 + c16][h * 32 + q16 * 8];
            for (int ct = 0; ct < 4; ++ct) {
                short8 vf = *(const short8*)&vlds[wv_ * 64 + ct * 16 + c16][h * 32 + q16 * 8];
                for (int jt = 0; jt < 4; ++jt)
                    acc[jt][ct] = __builtin_amdgcn_mfma_f32_16x16x32_bf16(pf[jt], vf, acc[jt][ct], 0, 0, 0);
            }
        }
    }
    if (c16 < 4) {
        float lv = (c16 == 0) ? l_r[0] : (c16 == 1) ? l_r[1] : (c16 == 2) ? l_r[2] : l_r[3];
        l_sh[wv_ * 16 + q16 * 4 + c16] = lv;
    }
    __syncthreads();
    float gl = gamma_p[0] / l_sh[lane];     // per j-row = jbase+lane
    const float* xbb = x + (size_t)b * CC * NN;
    float* obb = out + (size_t)b * CC * NN;
    // epilogue: LDS transpose per wave (16c at a time), coalesced stores
    for (int sub = 0; sub < 4; ++sub) {
        for (int jt = 0; jt < 4; ++jt) {
            floatx4 v = acc[jt][sub];
            float* orow = &obuf[wv_][c16][jt * 16 + q16 * 4];
            orow[0] = v[0]; orow[1] = v[1]; orow[2] = v[2]; orow[3] = v[3];
        }
        __syncthreads();
        int cbase = wv_ * 64 + sub * 16;
        for (int i = 0; i < 16; ++i) {
            size_t oidx = (size_t)(cbase + i) * NN + jbase + lane;
            obb[oidx] = fmaf(gl, obuf[wv_][i][lane], xbb[oidx]);
        }
        __syncthreads();
    }
}

extern "C" void kernel_launch(void* const* d_in, const int* in_sizes, int n_in,
                              void* d_out, int out_size, void* d_ws, size_t ws_size,
                              hipStream_t stream) {
    const float* x     = (const float*)d_in[0];
    const float* wq    = (const float*)d_in[1];
    const float* bq    = (const float*)d_in[2];
    const float* wk    = (const float*)d_in[3];
    const float* bk    = (const float*)d_in[4];
    const float* wv    = (const float*)d_in[5];
    const float* bv    = (const float*)d_in[6];
    const float* gamma = (const float*)d_in[7];
    const float* eps_q = (const float*)d_in[8];
    const float* eps_k = (const float*)d_in[9];
    float* out = (float*)d_out;

    char* ws = (char*)d_ws;
    float* qraw = (float*)ws;                              // 1 MB
    float* kraw = (float*)(ws + (1u << 20));               // 1 MB
    float* nu2  = (float*)(ws + (2u << 20));               // 512 B
    unsigned short* qb = (unsigned short*)(ws + (2u << 20) + 4096);  // 512 KB
    unsigned short* kb = qb + (size_t)NB * NN * C16;                 // 512 KB
    unsigned short* vb = kb + (size_t)NB * NN * C16;                 // 8 MB

    conv_qk_kernel<<<dim3(NB * HH), dim3(512), 0, stream>>>(x, wq, bq, wk, bk, qraw, kraw);
    frn_stats_kernel<<<dim3(128), dim3(256), 0, stream>>>(qraw, kraw, nu2);
    frn_mish_kernel<<<dim3(128), dim3(256), 0, stream>>>(qraw, kraw, nu2, eps_q, eps_k, qb, kb);
    conv_v_kernel<<<dim3(NB * 64), dim3(256), 0, stream>>>(x, wv, bv, vb);
    attn_kernel<<<dim3(64, NB), dim3(256), 0, stream>>>(qb, kb, vb, x, gamma, out);
}

// Round 2
// 352.091 us; speedup vs baseline: 1.3576x; 1.3576x over previous
//
#include <hip/hip_runtime.h>
#include <stdint.h>

#define NB 4
#define CC 256
#define C16 16
#define HH 64
#define WW 64
#define NN 4096

typedef __attribute__((ext_vector_type(8))) short short8;
typedef __attribute__((ext_vector_type(4))) float floatx4;

__device__ __forceinline__ unsigned short f2bf(float f) {
    union { float f; unsigned u; } v; v.f = f;
    unsigned r = v.u + 0x7fffu + ((v.u >> 16) & 1u);
    return (unsigned short)(r >> 16);
}

// ---------------- cast x -> xT bf16 [b][n][c] (LDS transpose) ----------------
__global__ __launch_bounds__(256) void cast_x_kernel(
        const float* __restrict__ x, unsigned short* __restrict__ xT) {
    __shared__ float tile[64][65];
    int nt = blockIdx.x, ct = blockIdx.y, b = blockIdx.z;
    int n0 = nt * 64, c0 = ct * 64;
    int ln = threadIdx.x & 63, grp = threadIdx.x >> 6;
    const float* xb = x + ((size_t)b * CC + c0) * NN + n0;
    for (int i = 0; i < 16; ++i) {
        int c = i * 4 + grp;
        tile[c][ln] = xb[(size_t)c * NN + ln];
    }
    __syncthreads();
    unsigned short* xtb = xT + ((size_t)b * NN + n0) * CC + c0;
    for (int i = 0; i < 16; ++i) {
        int n = i * 4 + grp;
        xtb[(size_t)n * CC + ln] = f2bf(tile[ln][n]);
    }
}

// ---------------- cast wv -> bf16 ----------------
__global__ __launch_bounds__(256) void cast_wv_kernel(
        const float* __restrict__ wv, unsigned short* __restrict__ wvb) {
    int idx = (blockIdx.x * 256 + threadIdx.x) * 4;
    float4 v = *(const float4*)(wv + idx);
    ushort4 o;
    o.x = f2bf(v.x); o.y = f2bf(v.y); o.z = f2bf(v.z); o.w = f2bf(v.w);
    *(ushort4*)(wvb + idx) = o;
}

// ---------------- q conv (1x3) + k conv (3x1) via MFMA im2col ----------------
__global__ __launch_bounds__(256) void conv_qk_mfma(
        const unsigned short* __restrict__ xT, const float* __restrict__ wq,
        const float* __restrict__ bq, const float* __restrict__ wk,
        const float* __restrict__ bk, float* __restrict__ qraw,
        float* __restrict__ kraw) {
    int h = blockIdx.x, b = blockIdx.y;
    int tid = threadIdx.x;
    int wv_ = tid >> 6, lane = tid & 63;
    int q16 = lane >> 4, c16 = lane & 15;
    int n = h * 64 + wv_ * 16 + c16;   // global n within batch
    int w = n & 63;
    bool vm1 = (w != 0), vp1 = (w != 63);
    bool vm64 = (h != 0), vp64 = (h != 63);
    short8 zero8 = {0, 0, 0, 0, 0, 0, 0, 0};
    floatx4 accq = {0.f, 0.f, 0.f, 0.f}, acck = {0.f, 0.f, 0.f, 0.f};
    const unsigned short* xb = xT + (size_t)b * NN * CC;
    const float* wqo = wq + c16 * 768;  // A-row m = o = c16
    const float* wko = wk + c16 * 768;
    for (int kc = 0; kc < 8; ++kc) {
        int ko = kc * 32 + q16 * 8;
        short8 b0 = *(const short8*)(xb + (size_t)n * CC + ko);
        short8 bm1 = vm1 ? *(const short8*)(xb + (size_t)(n - 1) * CC + ko) : zero8;
        short8 bp1 = vp1 ? *(const short8*)(xb + (size_t)(n + 1) * CC + ko) : zero8;
        short8 bm64 = vm64 ? *(const short8*)(xb + (size_t)(n - 64) * CC + ko) : zero8;
        short8 bp64 = vp64 ? *(const short8*)(xb + (size_t)(n + 64) * CC + ko) : zero8;
        short8 aq0, aq1, aq2, ak0, ak1, ak2;
#pragma unroll
        for (int j = 0; j < 8; ++j) {
            int c3 = (ko + j) * 3;
            aq0[j] = (short)f2bf(wqo[c3 + 0]);
            aq1[j] = (short)f2bf(wqo[c3 + 1]);
            aq2[j] = (short)f2bf(wqo[c3 + 2]);
            ak0[j] = (short)f2bf(wko[c3 + 0]);
            ak1[j] = (short)f2bf(wko[c3 + 1]);
            ak2[j] = (short)f2bf(wko[c3 + 2]);
        }
        accq = __builtin_amdgcn_mfma_f32_16x16x32_bf16(aq0, bm1, accq, 0, 0, 0);
        accq = __builtin_amdgcn_mfma_f32_16x16x32_bf16(aq1, b0, accq, 0, 0, 0);
        accq = __builtin_amdgcn_mfma_f32_16x16x32_bf16(aq2, bp1, accq, 0, 0, 0);
        acck = __builtin_amdgcn_mfma_f32_16x16x32_bf16(ak0, bm64, acck, 0, 0, 0);
        acck = __builtin_amdgcn_mfma_f32_16x16x32_bf16(ak1, b0, acck, 0, 0, 0);
        acck = __builtin_amdgcn_mfma_f32_16x16x32_bf16(ak2, bp64, acck, 0, 0, 0);
    }
#pragma unroll
    for (int r = 0; r < 4; ++r) {
        int o = q16 * 4 + r;
        qraw[(size_t)(b * C16 + o) * NN + n] = accq[r] + bq[o];
        kraw[(size_t)(b * C16 + o) * NN + n] = acck[r] + bk[o];
    }
}

// ---------------- FRN stats: nu2[b,o] = mean over N of raw^2 ----------------
__global__ __launch_bounds__(256) void frn_stats_kernel(
        const float* __restrict__ qraw, const float* __restrict__ kraw,
        float* __restrict__ nu2) {
    int blk = blockIdx.x;                 // 0..63 q, 64..127 k
    const float* src = (blk & 64) ? kraw : qraw;
    int bo = blk & 63;
    const floatx4* p = (const floatx4*)(src + (size_t)bo * NN);
    float s = 0.f;
    for (int i = 0; i < 4; ++i) {
        floatx4 v = p[threadIdx.x + 256 * i];
        s += v[0]*v[0] + v[1]*v[1] + v[2]*v[2] + v[3]*v[3];
    }
    for (int off = 1; off < 64; off <<= 1) s += __shfl_xor(s, off, 64);
    __shared__ float part[4];
    if ((threadIdx.x & 63) == 0) part[threadIdx.x >> 6] = s;
    __syncthreads();
    if (threadIdx.x == 0)
        nu2[blk] = (part[0] + part[1] + part[2] + part[3]) * (1.f / (float)NN);
}

// ---------------- FRN normalize + Mish, transpose-write bf16 [b][n][16] ----------------
__global__ __launch_bounds__(256) void frn_mish_kernel(
        const float* __restrict__ qraw, const float* __restrict__ kraw,
        const float* __restrict__ nu2, const float* __restrict__ eps_q,
        const float* __restrict__ eps_k, unsigned short* __restrict__ qb,
        unsigned short* __restrict__ kb) {
    int blk = blockIdx.x;
    int tensor = blk >> 6;
    int b = (blk >> 4) & 3;
    int ch = blk & 15;
    const float* raw = tensor ? kraw : qraw;
    const float* eps = tensor ? eps_k : eps_q;
    unsigned short* outp = tensor ? kb : qb;
    const float* nu = nu2 + tensor * 64 + b * C16;
    int n = ch * 256 + threadIdx.x;
    union { unsigned short s[16]; uint4 u[2]; } pk;
    for (int o = 0; o < C16; ++o) {
        float r = raw[(size_t)(b * C16 + o) * NN + n];
        float v = r * rsqrtf(nu[o] + fabsf(eps[o]));
        float sp = fmaxf(v, 0.f) + log1pf(expf(-fabsf(v)));   // stable softplus
        pk.s[o] = f2bf(v * tanhf(sp));
    }
    uint4* dst = (uint4*)(outp + (size_t)(b * NN + n) * C16);
    dst[0] = pk.u[0];
    dst[1] = pk.u[1];
}

// ---------------- v = 1x1 conv via MFMA, bf16 out [b][c][n] ----------------
__global__ __launch_bounds__(256) void conv_v_mfma(
        const unsigned short* __restrict__ xT, const unsigned short* __restrict__ wvb,
        const float* __restrict__ bv, unsigned short* __restrict__ vb) {
    int ntile = blockIdx.x, b = blockIdx.y, ch = blockIdx.z;   // ch: 0..1
    int tid = threadIdx.x;
    int wv_ = tid >> 6, lane = tid & 63;
    int q16 = lane >> 4, c16 = lane & 15;
    int n0 = ntile * 64;
    int cb = ch * 128 + wv_ * 32;
    floatx4 fzero = {0.f, 0.f, 0.f, 0.f};
    floatx4 acc[2][4];
    for (int ct = 0; ct < 2; ++ct)
        for (int nt = 0; nt < 4; ++nt) acc[ct][nt] = fzero;
    const unsigned short* xb = xT + ((size_t)b * NN + n0) * CC;
    for (int kc = 0; kc < 8; ++kc) {
        int ko = kc * 32 + q16 * 8;
        short8 a0 = *(const short8*)(wvb + (size_t)(cb + c16) * CC + ko);
        short8 a1 = *(const short8*)(wvb + (size_t)(cb + 16 + c16) * CC + ko);
        short8 bf[4];
#pragma unroll
        for (int nt = 0; nt < 4; ++nt)
            bf[nt] = *(const short8*)(xb + (size_t)(nt * 16 + c16) * CC + ko);
#pragma unroll
        for (int nt = 0; nt < 4; ++nt) {
            acc[0][nt] = __builtin_amdgcn_mfma_f32_16x16x32_bf16(a0, bf[nt], acc[0][nt], 0, 0, 0);
            acc[1][nt] = __builtin_amdgcn_mfma_f32_16x16x32_bf16(a1, bf[nt], acc[1][nt], 0, 0, 0);
        }
    }
#pragma unroll
    for (int ct = 0; ct < 2; ++ct)
        for (int nt = 0; nt < 4; ++nt)
            for (int r = 0; r < 4; ++r) {
                int c = cb + ct * 16 + q16 * 4 + r;
                int nn = n0 + nt * 16 + c16;
                vb[(size_t)(b * CC + c) * NN + nn] = f2bf(acc[ct][nt][r] + bv[c]);
            }
}

// ---------------- flash attention (c-split 4) + epilogue gamma*W + x ----------------
// grid (64 j-tiles, B, 4 c-splits). block 256 = 4 waves. Each wave: S rows
// [16w,16w+16); PV tile 64j x 16c (c range cb + [16w, 16w+16)).
__global__ __launch_bounds__(256) void attn_kernel(
        const unsigned short* __restrict__ qb, const unsigned short* __restrict__ kb,
        const unsigned short* __restrict__ vb, const float* __restrict__ x,
        const float* __restrict__ gamma_p, float* __restrict__ out) {
    __shared__ __align__(16) unsigned short sbuf[2 * 64 * 72]; // vlds | plds; epilogue: obuf
    __shared__ __align__(16) float alpha_sh[64];
    __shared__ __align__(16) float l_sh[64];
    unsigned short* vlds = sbuf;
    unsigned short* plds = sbuf + 64 * 72;

    int tid = threadIdx.x;
    int wv_ = __builtin_amdgcn_readfirstlane(tid >> 6);
    int lane = tid & 63;
    int q16 = lane >> 4, c16 = lane & 15;
    int b = blockIdx.y;
    int jbase = blockIdx.x * 64;
    int cb = blockIdx.z * 64;

    short8 zero8 = {0, 0, 0, 0, 0, 0, 0, 0};
    floatx4 fzero = {0.f, 0.f, 0.f, 0.f};

    // Q A-frag: A[m=c16][k=q16*8+t]; d-dim 16 padded to K=32 with zeros
    short8 aq = zero8;
    if (q16 < 2)
        aq = *(const short8*)(qb + (size_t)(b * NN + jbase + wv_ * 16 + c16) * C16 + q16 * 8);

    floatx4 acc[4];
    for (int jt = 0; jt < 4; ++jt) acc[jt] = fzero;
    float m_r[4] = {-INFINITY, -INFINITY, -INFINITY, -INFINITY};
    float l_r[4] = {0.f, 0.f, 0.f, 0.f};

    const unsigned short* vbb = vb + ((size_t)b * CC + cb) * NN;
    const unsigned short* kbb = kb + (size_t)b * NN * C16;

    // V staging map: granule g -> row g>>3 (c-local), col (g&7)*8
    int c0_ = tid >> 3, o0_ = (tid & 7) * 8;             // rows 0..31
    int c1_ = c0_ + 32, o1_ = o0_;                       // rows 32..63
    // prefetch iter 0
    uint4 vr0 = *(const uint4*)(vbb + (size_t)c0_ * NN + o0_);
    uint4 vr1 = *(const uint4*)(vbb + (size_t)c1_ * NN + o1_);
    short8 kf[4];
#pragma unroll
    for (int s = 0; s < 4; ++s)
        kf[s] = (q16 < 2) ? *(const short8*)(kbb + (size_t)(s * 16 + c16) * C16 + q16 * 8) : zero8;

    for (int it = 0; it < 64; ++it) {
        __syncthreads();   // prev iter's LDS reads done
        *(uint4*)&vlds[c0_ * 72 + o0_] = vr0;
        *(uint4*)&vlds[c1_ * 72 + o1_] = vr1;
        // S = Q K^T for this wave's 16 rows
        floatx4 sv[4];
#pragma unroll
        for (int s = 0; s < 4; ++s)
            sv[s] = __builtin_amdgcn_mfma_f32_16x16x32_bf16(aq, kf[s], fzero, 0, 0, 0);
        // prefetch next iter's V tile + K frags (overlaps softmax + PV)
        int n1 = ((it + 1) & 63) * 64;
        vr0 = *(const uint4*)(vbb + (size_t)c0_ * NN + n1 + o0_);
        vr1 = *(const uint4*)(vbb + (size_t)c1_ * NN + n1 + o1_);
#pragma unroll
        for (int s = 0; s < 4; ++s)
            kf[s] = (q16 < 2) ? *(const short8*)(kbb + (size_t)(n1 + s * 16 + c16) * C16 + q16 * 8) : zero8;
        // online softmax: C-layout row = q16*4+r, col = c16 + 16s
        float al[4];
#pragma unroll
        for (int r = 0; r < 4; ++r) {
            float mt = fmaxf(fmaxf(sv[0][r], sv[1][r]), fmaxf(sv[2][r], sv[3][r]));
            mt = fmaxf(mt, __shfl_xor(mt, 1, 64));
            mt = fmaxf(mt, __shfl_xor(mt, 2, 64));
            mt = fmaxf(mt, __shfl_xor(mt, 4, 64));
            mt = fmaxf(mt, __shfl_xor(mt, 8, 64));
            float mn = fmaxf(m_r[r], mt);
            al[r] = __expf(m_r[r] - mn);
            m_r[r] = mn;
            float lt = 0.f;
            int prow = wv_ * 16 + q16 * 4 + r;
#pragma unroll
            for (int s = 0; s < 4; ++s) {
                float pv = __expf(sv[s][r] - mn);
                lt += pv;
                plds[prow * 72 + s * 16 + c16] = f2bf(pv);
            }
            lt += __shfl_xor(lt, 1, 64);
            lt += __shfl_xor(lt, 2, 64);
            lt += __shfl_xor(lt, 4, 64);
            lt += __shfl_xor(lt, 8, 64);
            l_r[r] = l_r[r] * al[r] + lt;
        }
        if (c16 < 4) {
            float a = (c16 == 0) ? al[0] : (c16 == 1) ? al[1] : (c16 == 2) ? al[2] : al[3];
            alpha_sh[wv_ * 16 + q16 * 4 + c16] = a;
        }
        __syncthreads();   // plds + alpha_sh + vlds ready
        // rescale O (rows j-rel = jt*16 + q16*4 + r)
#pragma unroll
        for (int jt = 0; jt < 4; ++jt) {
            floatx4 a4 = *(const floatx4*)&alpha_sh[jt * 16 + q16 * 4];
            acc[jt][0] *= a4[0];
            acc[jt][1] *= a4[1];
            acc[jt][2] *= a4[2];
            acc[jt][3] *= a4[3];
        }
        // PV: A = P[j][n], B[k=n][c] = v[c][n]; wave's c rows = wv_*16 + c16
#pragma unroll
        for (int h = 0; h < 2; ++h) {
            short8 vf = *(const short8*)&vlds[(wv_ * 16 + c16) * 72 + h * 32 + q16 * 8];
#pragma unroll
            for (int jt = 0; jt < 4; ++jt) {
                short8 pf = *(const short8*)&plds[(jt * 16 + c16) * 72 + h * 32 + q16 * 8];
                acc[jt] = __builtin_amdgcn_mfma_f32_16x16x32_bf16(pf, vf, acc[jt], 0, 0, 0);
            }
        }
    }
    if (c16 < 4) {
        float lv = (c16 == 0) ? l_r[0] : (c16 == 1) ? l_r[1] : (c16 == 2) ? l_r[2] : l_r[3];
        l_sh[wv_ * 16 + q16 * 4 + c16] = lv;
    }
    __syncthreads();       // last PV reads done; l_sh visible
    float gl = gamma_p[0] / l_sh[lane];     // per j-row = jbase+lane
    // epilogue: per-wave LDS transpose (obuf aliases vlds/plds region)
    float* ob = (float*)sbuf + wv_ * 16 * 67;
#pragma unroll
    for (int jt = 0; jt < 4; ++jt) {
        ob[c16 * 67 + jt * 16 + q16 * 4 + 0] = acc[jt][0];
        ob[c16 * 67 + jt * 16 + q16 * 4 + 1] = acc[jt][1];
        ob[c16 * 67 + jt * 16 + q16 * 4 + 2] = acc[jt][2];
        ob[c16 * 67 + jt * 16 + q16 * 4 + 3] = acc[jt][3];
    }
    __syncthreads();
    const float* xbb = x + (size_t)b * CC * NN;
    float* obb = out + (size_t)b * CC * NN;
    for (int i = 0; i < 16; ++i) {
        int c = cb + wv_ * 16 + i;
        size_t oidx = (size_t)c * NN + jbase + lane;
        obb[oidx] = fmaf(gl, ob[i * 67 + lane], xbb[oidx]);
    }
}

extern "C" void kernel_launch(void* const* d_in, const int* in_sizes, int n_in,
                              void* d_out, int out_size, void* d_ws, size_t ws_size,
                              hipStream_t stream) {
    const float* x     = (const float*)d_in[0];
    const float* wq    = (const float*)d_in[1];
    const float* bq    = (const float*)d_in[2];
    const float* wk    = (const float*)d_in[3];
    const float* bk    = (const float*)d_in[4];
    const float* wv    = (const float*)d_in[5];
    const float* bv    = (const float*)d_in[6];
    const float* gamma = (const float*)d_in[7];
    const float* eps_q = (const float*)d_in[8];
    const float* eps_k = (const float*)d_in[9];
    float* out = (float*)d_out;

    char* ws = (char*)d_ws;
    float* qraw = (float*)ws;                                        // 1 MB
    float* kraw = (float*)(ws + (1u << 20));                         // 1 MB
    float* nu2  = (float*)(ws + (2u << 20));                         // 512 B
    unsigned short* qb = (unsigned short*)(ws + (2u << 20) + 4096);  // 512 KB
    unsigned short* kb = qb + (size_t)NB * NN * C16;                 // 512 KB
    unsigned short* vb = kb + (size_t)NB * NN * C16;                 // 8 MB
    unsigned short* xT = vb + (size_t)NB * CC * NN;                  // 8 MB
    unsigned short* wvb = xT + (size_t)NB * NN * CC;                 // 128 KB

    cast_x_kernel<<<dim3(64, 4, NB), dim3(256), 0, stream>>>(x, xT);
    cast_wv_kernel<<<dim3(64), dim3(256), 0, stream>>>(wv, wvb);
    conv_qk_mfma<<<dim3(64, NB), dim3(256), 0, stream>>>(xT, wq, bq, wk, bk, qraw, kraw);
    frn_stats_kernel<<<dim3(128), dim3(256), 0, stream>>>(qraw, kraw, nu2);
    frn_mish_kernel<<<dim3(128), dim3(256), 0, stream>>>(qraw, kraw, nu2, eps_q, eps_k, qb, kb);
    conv_v_mfma<<<dim3(64, NB, 2), dim3(256), 0, stream>>>(xT, wvb, bv, vb);
    attn_kernel<<<dim3(64, NB, 4), dim3(256), 0, stream>>>(qb, kb, vb, x, gamma, out);
}

// Round 3
// 342.558 us; speedup vs baseline: 1.3954x; 1.0278x over previous
//
#include <hip/hip_runtime.h>
#include <stdint.h>

#define NB 4
#define CC 256
#define C16 16
#define HH 64
#define WW 64
#define NN 4096

typedef __attribute__((ext_vector_type(8))) short short8;
typedef __attribute__((ext_vector_type(4))) float floatx4;

__device__ __forceinline__ unsigned short f2bf(float f) {
    union { float f; unsigned u; } v; v.f = f;
    unsigned r = v.u + 0x7fffu + ((v.u >> 16) & 1u);
    return (unsigned short)(r >> 16);
}

// ---------------- cast x -> xT bf16 [b][n][c] (LDS transpose) ----------------
__global__ __launch_bounds__(256) void cast_x_kernel(
        const float* __restrict__ x, unsigned short* __restrict__ xT) {
    __shared__ float tile[64][65];
    int nt = blockIdx.x, ct = blockIdx.y, b = blockIdx.z;
    int n0 = nt * 64, c0 = ct * 64;
    int ln = threadIdx.x & 63, grp = threadIdx.x >> 6;
    const float* xb = x + ((size_t)b * CC + c0) * NN + n0;
    for (int i = 0; i < 16; ++i) {
        int c = i * 4 + grp;
        tile[c][ln] = xb[(size_t)c * NN + ln];
    }
    __syncthreads();
    unsigned short* xtb = xT + ((size_t)b * NN + n0) * CC + c0;
    for (int i = 0; i < 16; ++i) {
        int n = i * 4 + grp;
        xtb[(size_t)n * CC + ln] = f2bf(tile[ln][n]);
    }
}

// ---------------- cast wv -> bf16 ----------------
__global__ __launch_bounds__(256) void cast_wv_kernel(
        const float* __restrict__ wv, unsigned short* __restrict__ wvb) {
    int idx = (blockIdx.x * 256 + threadIdx.x) * 4;
    float4 v = *(const float4*)(wv + idx);
    ushort4 o;
    o.x = f2bf(v.x); o.y = f2bf(v.y); o.z = f2bf(v.z); o.w = f2bf(v.w);
    *(ushort4*)(wvb + idx) = o;
}

// ---------------- cast wq/wk -> bf16 A-frag layout [tensor][tap][o][c] ----------------
__global__ __launch_bounds__(256) void cast_wqk_kernel(
        const float* __restrict__ wq, const float* __restrict__ wk,
        unsigned short* __restrict__ wqkb) {
    int idx = blockIdx.x * 256 + threadIdx.x;     // 0..24575
    int t = idx / 12288;
    int i = idx - t * 12288;
    int tap = i >> 12, o = (i >> 8) & 15, c = i & 255;
    const float* src = t ? wk : wq;
    wqkb[idx] = f2bf(src[o * 768 + c * 3 + tap]);
}

// ---------------- q conv (1x3) + k conv (3x1) via MFMA im2col ----------------
__global__ __launch_bounds__(256) void conv_qk_mfma(
        const unsigned short* __restrict__ xT, const unsigned short* __restrict__ wqkb,
        const float* __restrict__ bq, const float* __restrict__ bk,
        float* __restrict__ qraw, float* __restrict__ kraw) {
    int h = blockIdx.x, b = blockIdx.y;
    int tid = threadIdx.x;
    int wv_ = tid >> 6, lane = tid & 63;
    int q16 = lane >> 4, c16 = lane & 15;
    int n = h * 64 + wv_ * 16 + c16;   // global n within batch
    int w = n & 63;
    bool vm1 = (w != 0), vp1 = (w != 63);
    bool vm64 = (h != 0), vp64 = (h != 63);
    short8 zero8 = {0, 0, 0, 0, 0, 0, 0, 0};
    floatx4 accq = {0.f, 0.f, 0.f, 0.f}, acck = {0.f, 0.f, 0.f, 0.f};
    const unsigned short* xb = xT + (size_t)b * NN * CC;
    const unsigned short* wrow = wqkb + c16 * 256;   // A-row m = o = c16
    for (int kc = 0; kc < 8; ++kc) {
        int ko = kc * 32 + q16 * 8;
        short8 b0 = *(const short8*)(xb + (size_t)n * CC + ko);
        short8 bm1 = vm1 ? *(const short8*)(xb + (size_t)(n - 1) * CC + ko) : zero8;
        short8 bp1 = vp1 ? *(const short8*)(xb + (size_t)(n + 1) * CC + ko) : zero8;
        short8 bm64 = vm64 ? *(const short8*)(xb + (size_t)(n - 64) * CC + ko) : zero8;
        short8 bp64 = vp64 ? *(const short8*)(xb + (size_t)(n + 64) * CC + ko) : zero8;
        short8 aq0 = *(const short8*)(wrow + 0 * 4096 + ko);
        short8 aq1 = *(const short8*)(wrow + 1 * 4096 + ko);
        short8 aq2 = *(const short8*)(wrow + 2 * 4096 + ko);
        short8 ak0 = *(const short8*)(wrow + 12288 + 0 * 4096 + ko);
        short8 ak1 = *(const short8*)(wrow + 12288 + 1 * 4096 + ko);
        short8 ak2 = *(const short8*)(wrow + 12288 + 2 * 4096 + ko);
        accq = __builtin_amdgcn_mfma_f32_16x16x32_bf16(aq0, bm1, accq, 0, 0, 0);
        accq = __builtin_amdgcn_mfma_f32_16x16x32_bf16(aq1, b0, accq, 0, 0, 0);
        accq = __builtin_amdgcn_mfma_f32_16x16x32_bf16(aq2, bp1, accq, 0, 0, 0);
        acck = __builtin_amdgcn_mfma_f32_16x16x32_bf16(ak0, bm64, acck, 0, 0, 0);
        acck = __builtin_amdgcn_mfma_f32_16x16x32_bf16(ak1, b0, acck, 0, 0, 0);
        acck = __builtin_amdgcn_mfma_f32_16x16x32_bf16(ak2, bp64, acck, 0, 0, 0);
    }
#pragma unroll
    for (int r = 0; r < 4; ++r) {
        int o = q16 * 4 + r;
        qraw[(size_t)(b * C16 + o) * NN + n] = accq[r] + bq[o];
        kraw[(size_t)(b * C16 + o) * NN + n] = acck[r] + bk[o];
    }
}

// ---------------- FRN stats: nu2[b,o] = mean over N of raw^2 ----------------
__global__ __launch_bounds__(256) void frn_stats_kernel(
        const float* __restrict__ qraw, const float* __restrict__ kraw,
        float* __restrict__ nu2) {
    int blk = blockIdx.x;                 // 0..63 q, 64..127 k
    const float* src = (blk & 64) ? kraw : qraw;
    int bo = blk & 63;
    const floatx4* p = (const floatx4*)(src + (size_t)bo * NN);
    float s = 0.f;
    for (int i = 0; i < 4; ++i) {
        floatx4 v = p[threadIdx.x + 256 * i];
        s += v[0]*v[0] + v[1]*v[1] + v[2]*v[2] + v[3]*v[3];
    }
    for (int off = 1; off < 64; off <<= 1) s += __shfl_xor(s, off, 64);
    __shared__ float part[4];
    if ((threadIdx.x & 63) == 0) part[threadIdx.x >> 6] = s;
    __syncthreads();
    if (threadIdx.x == 0)
        nu2[blk] = (part[0] + part[1] + part[2] + part[3]) * (1.f / (float)NN);
}

// ---------------- FRN normalize + Mish, transpose-write bf16 [b][n][16] ----------------
__global__ __launch_bounds__(256) void frn_mish_kernel(
        const float* __restrict__ qraw, const float* __restrict__ kraw,
        const float* __restrict__ nu2, const float* __restrict__ eps_q,
        const float* __restrict__ eps_k, unsigned short* __restrict__ qb,
        unsigned short* __restrict__ kb) {
    int blk = blockIdx.x;
    int tensor = blk >> 6;
    int b = (blk >> 4) & 3;
    int ch = blk & 15;
    const float* raw = tensor ? kraw : qraw;
    const float* eps = tensor ? eps_k : eps_q;
    unsigned short* outp = tensor ? kb : qb;
    const float* nu = nu2 + tensor * 64 + b * C16;
    int n = ch * 256 + threadIdx.x;
    union { unsigned short s[16]; uint4 u[2]; } pk;
    for (int o = 0; o < C16; ++o) {
        float r = raw[(size_t)(b * C16 + o) * NN + n];
        float v = r * rsqrtf(nu[o] + fabsf(eps[o]));
        float sp = fmaxf(v, 0.f) + log1pf(expf(-fabsf(v)));   // stable softplus
        pk.s[o] = f2bf(v * tanhf(sp));
    }
    uint4* dst = (uint4*)(outp + (size_t)(b * NN + n) * C16);
    dst[0] = pk.u[0];
    dst[1] = pk.u[1];
}

// ---------------- v = 1x1 conv via MFMA, bf16 out [b][c][n] ----------------
__global__ __launch_bounds__(256) void conv_v_mfma(
        const unsigned short* __restrict__ xT, const unsigned short* __restrict__ wvb,
        const float* __restrict__ bv, unsigned short* __restrict__ vb) {
    int ntile = blockIdx.x, b = blockIdx.y, ch = blockIdx.z;   // ch: 0..1
    int tid = threadIdx.x;
    int wv_ = tid >> 6, lane = tid & 63;
    int q16 = lane >> 4, c16 = lane & 15;
    int n0 = ntile * 64;
    int cb = ch * 128 + wv_ * 32;
    floatx4 fzero = {0.f, 0.f, 0.f, 0.f};
    floatx4 acc[2][4];
    for (int ct = 0; ct < 2; ++ct)
        for (int nt = 0; nt < 4; ++nt) acc[ct][nt] = fzero;
    const unsigned short* xb = xT + ((size_t)b * NN + n0) * CC;
    for (int kc = 0; kc < 8; ++kc) {
        int ko = kc * 32 + q16 * 8;
        short8 a0 = *(const short8*)(wvb + (size_t)(cb + c16) * CC + ko);
        short8 a1 = *(const short8*)(wvb + (size_t)(cb + 16 + c16) * CC + ko);
        short8 bf[4];
#pragma unroll
        for (int nt = 0; nt < 4; ++nt)
            bf[nt] = *(const short8*)(xb + (size_t)(nt * 16 + c16) * CC + ko);
#pragma unroll
        for (int nt = 0; nt < 4; ++nt) {
            acc[0][nt] = __builtin_amdgcn_mfma_f32_16x16x32_bf16(a0, bf[nt], acc[0][nt], 0, 0, 0);
            acc[1][nt] = __builtin_amdgcn_mfma_f32_16x16x32_bf16(a1, bf[nt], acc[1][nt], 0, 0, 0);
        }
    }
#pragma unroll
    for (int ct = 0; ct < 2; ++ct)
        for (int nt = 0; nt < 4; ++nt)
            for (int r = 0; r < 4; ++r) {
                int c = cb + ct * 16 + q16 * 4 + r;
                int nn = n0 + nt * 16 + c16;
                vb[(size_t)(b * CC + c) * NN + nn] = f2bf(acc[ct][nt][r] + bv[c]);
            }
}

// ---------------- pre-pass: true row max of S, m[b][j] ----------------
__global__ __launch_bounds__(256) void row_max_kernel(
        const unsigned short* __restrict__ qb, const unsigned short* __restrict__ kb,
        float* __restrict__ mrow) {
    int jt = blockIdx.x, b = blockIdx.y;
    int tid = threadIdx.x;
    int wv_ = tid >> 6, lane = tid & 63;
    int q16 = lane >> 4, c16 = lane & 15;
    int jb = jt * 64;
    const unsigned short* qbb = qb + (size_t)b * NN * C16;
    const unsigned short* kbb = kb + (size_t)b * NN * C16;
    short8 zero8 = {0, 0, 0, 0, 0, 0, 0, 0};
    floatx4 fzero = {0.f, 0.f, 0.f, 0.f};
    short8 aq = (q16 < 2) ? *(const short8*)(qbb + (size_t)(jb + wv_ * 16 + c16) * C16 + q16 * 8) : zero8;
    float m_r[4] = {-INFINITY, -INFINITY, -INFINITY, -INFINITY};
    short8 kf[4];
#pragma unroll
    for (int s = 0; s < 4; ++s)
        kf[s] = (q16 < 2) ? *(const short8*)(kbb + (size_t)(s * 16 + c16) * C16 + q16 * 8) : zero8;
    for (int it = 0; it < 64; ++it) {
        int n1 = ((it + 1) & 63) * 64;
        short8 kn[4];
#pragma unroll
        for (int s = 0; s < 4; ++s)
            kn[s] = (q16 < 2) ? *(const short8*)(kbb + (size_t)(n1 + s * 16 + c16) * C16 + q16 * 8) : zero8;
#pragma unroll
        for (int s = 0; s < 4; ++s) {
            floatx4 sv = __builtin_amdgcn_mfma_f32_16x16x32_bf16(aq, kf[s], fzero, 0, 0, 0);
#pragma unroll
            for (int r = 0; r < 4; ++r) m_r[r] = fmaxf(m_r[r], sv[r]);
        }
#pragma unroll
        for (int s = 0; s < 4; ++s) kf[s] = kn[s];
    }
#pragma unroll
    for (int r = 0; r < 4; ++r) {
        m_r[r] = fmaxf(m_r[r], __shfl_xor(m_r[r], 1, 64));
        m_r[r] = fmaxf(m_r[r], __shfl_xor(m_r[r], 2, 64));
        m_r[r] = fmaxf(m_r[r], __shfl_xor(m_r[r], 4, 64));
        m_r[r] = fmaxf(m_r[r], __shfl_xor(m_r[r], 8, 64));
    }
    if (c16 == 0) {
#pragma unroll
        for (int r = 0; r < 4; ++r)
            mrow[(size_t)b * NN + jb + wv_ * 16 + q16 * 4 + r] = m_r[r];
    }
}

// ---------------- attention, fixed row max (no online softmax) ----------------
// grid 512 1-D: id&1 = c-split (128 c each), (id>>1)&3 = b, id>>3 = 64-j tile.
// XCD swizzle: consecutive ids -> different XCDs get distinct (cs,b) -> V slice
// (1 MB) stays L2-resident. Block 256 = 4 waves; wave w: S^T kcols [16w,16w+16),
// PV c-slice [32w, 32w+32).
__global__ __launch_bounds__(256) void attn_kernel(
        const unsigned short* __restrict__ qb, const unsigned short* __restrict__ kb,
        const unsigned short* __restrict__ vb, const float* __restrict__ mrow,
        const float* __restrict__ x, const float* __restrict__ gamma_p,
        float* __restrict__ out) {
    __shared__ __align__(16) unsigned short sbuf[(128 + 64) * 72];  // vlds | plds; epilogue obuf
    __shared__ float lpart[4][64];
    unsigned short* vlds = sbuf;
    unsigned short* plds = sbuf + 128 * 72;

    int tid = threadIdx.x;
    int wv_ = __builtin_amdgcn_readfirstlane(tid >> 6);
    int lane = tid & 63;
    int q16 = lane >> 4, c16 = lane & 15;
    int id = blockIdx.x;
    int cs = id & 1, b = (id >> 1) & 3, jt = id >> 3;
    int jbase = jt * 64, cb = cs * 128;

    short8 zero8 = {0, 0, 0, 0, 0, 0, 0, 0};
    floatx4 fzero = {0.f, 0.f, 0.f, 0.f};

    const unsigned short* qbb = qb + (size_t)b * NN * C16;
    const unsigned short* kbb = kb + (size_t)b * NN * C16;
    const unsigned short* vbb = vb + ((size_t)b * CC + cb) * NN;

    // loop-invariant Q B-frags (B[k=d][n=j]), and per-lane row max m[j]
    short8 qf[4];
    float m_s[4];
#pragma unroll
    for (int s = 0; s < 4; ++s) {
        qf[s] = (q16 < 2) ? *(const short8*)(qbb + (size_t)(jbase + s * 16 + c16) * C16 + q16 * 8) : zero8;
        m_s[s] = mrow[(size_t)b * NN + jbase + s * 16 + c16];
    }

    // V staging map: thread covers rows vrow+32i, 8-short chunk vcol
    int vrow = tid >> 3, vcol = (tid & 7) * 8;
    uint4 vr[4];
#pragma unroll
    for (int i = 0; i < 4; ++i)
        vr[i] = *(const uint4*)(vbb + (size_t)(vrow + 32 * i) * NN + vcol);
    // K A-frag (A[m=kcol][k=d]) for iter 0
    short8 ak = (q16 < 2) ? *(const short8*)(kbb + (size_t)(16 * wv_ + c16) * C16 + q16 * 8) : zero8;

    floatx4 acc[4][2];
#pragma unroll
    for (int j = 0; j < 4; ++j) { acc[j][0] = fzero; acc[j][1] = fzero; }
    float lsum[4] = {0.f, 0.f, 0.f, 0.f};

    for (int it = 0; it < 64; ++it) {
        __syncthreads();   // prev PV reads done
#pragma unroll
        for (int i = 0; i < 4; ++i)
            *(uint4*)&vlds[(vrow + 32 * i) * 72 + vcol] = vr[i];
        // S^T: C[m=kcol-local][n=j-local]
        floatx4 sv[4];
#pragma unroll
        for (int s = 0; s < 4; ++s)
            sv[s] = __builtin_amdgcn_mfma_f32_16x16x32_bf16(ak, qf[s], fzero, 0, 0, 0);
        // prefetch next iter (overlaps exp + PV)
        int n1 = ((it + 1) & 63) * 64;
#pragma unroll
        for (int i = 0; i < 4; ++i)
            vr[i] = *(const uint4*)(vbb + (size_t)(vrow + 32 * i) * NN + n1 + vcol);
        ak = (q16 < 2) ? *(const short8*)(kbb + (size_t)(n1 + 16 * wv_ + c16) * C16 + q16 * 8) : zero8;
        // P = exp(S - m[j]); lane: j = s*16+c16, kcols 16*wv_ + q16*4 + r (consecutive!)
#pragma unroll
        for (int s = 0; s < 4; ++s) {
            float p0 = __expf(sv[s][0] - m_s[s]);
            float p1 = __expf(sv[s][1] - m_s[s]);
            float p2 = __expf(sv[s][2] - m_s[s]);
            float p3 = __expf(sv[s][3] - m_s[s]);
            lsum[s] += (p0 + p1) + (p2 + p3);
            uint2 u;
            u.x = (unsigned)f2bf(p0) | ((unsigned)f2bf(p1) << 16);
            u.y = (unsigned)f2bf(p2) | ((unsigned)f2bf(p3) << 16);
            *(uint2*)&plds[(s * 16 + c16) * 72 + 16 * wv_ + q16 * 4] = u;
        }
        __syncthreads();   // vlds + plds ready
        // PV: A = P[j][k], B = vlds[c][k]; acc C[m=j-local][n=c-local]
#pragma unroll
        for (int kh = 0; kh < 2; ++kh) {
            short8 vf0 = *(const short8*)&vlds[(wv_ * 32 + c16) * 72 + kh * 32 + q16 * 8];
            short8 vf1 = *(const short8*)&vlds[(wv_ * 32 + 16 + c16) * 72 + kh * 32 + q16 * 8];
#pragma unroll
            for (int j = 0; j < 4; ++j) {
                short8 pf = *(const short8*)&plds[(j * 16 + c16) * 72 + kh * 32 + q16 * 8];
                acc[j][0] = __builtin_amdgcn_mfma_f32_16x16x32_bf16(pf, vf0, acc[j][0], 0, 0, 0);
                acc[j][1] = __builtin_amdgcn_mfma_f32_16x16x32_bf16(pf, vf1, acc[j][1], 0, 0, 0);
            }
        }
    }
    // final l reduction: sum over q16 lanes, then over waves via LDS
#pragma unroll
    for (int s = 0; s < 4; ++s) {
        lsum[s] += __shfl_xor(lsum[s], 16, 64);
        lsum[s] += __shfl_xor(lsum[s], 32, 64);
    }
    if (q16 == 0) {
#pragma unroll
        for (int s = 0; s < 4; ++s) lpart[wv_][s * 16 + c16] = lsum[s];
    }
    __syncthreads();       // also guards sbuf reuse below
    float l = lpart[0][lane] + lpart[1][lane] + lpart[2][lane] + lpart[3][lane];
    float gl = gamma_p[0] / l;   // per j-row = jbase + lane
    const float* xbb = x + (size_t)b * CC * NN;
    float* obb = out + (size_t)b * CC * NN;
    // epilogue: per-wave private LDS transpose (16 c rows x 64 j), stride 68 floats
    float* ob = (float*)sbuf + wv_ * 16 * 68;
#pragma unroll
    for (int ct = 0; ct < 2; ++ct) {
#pragma unroll
        for (int j = 0; j < 4; ++j) {
            floatx4 v = acc[j][ct];
            *(floatx4*)&ob[c16 * 68 + j * 16 + q16 * 4] = v;
        }
        // wave-internal LDS write->read; lockstep wave64, compiler inserts lgkmcnt
        int cbase = cb + wv_ * 32 + ct * 16;
#pragma unroll
        for (int i = 0; i < 16; ++i) {
            size_t oidx = (size_t)(cbase + i) * NN + jbase + lane;
            obb[oidx] = fmaf(gl, ob[i * 68 + lane], xbb[oidx]);
        }
    }
}

extern "C" void kernel_launch(void* const* d_in, const int* in_sizes, int n_in,
                              void* d_out, int out_size, void* d_ws, size_t ws_size,
                              hipStream_t stream) {
    const float* x     = (const float*)d_in[0];
    const float* wq    = (const float*)d_in[1];
    const float* bq    = (const float*)d_in[2];
    const float* wk    = (const float*)d_in[3];
    const float* bk    = (const float*)d_in[4];
    const float* wv    = (const float*)d_in[5];
    const float* bv    = (const float*)d_in[6];
    const float* gamma = (const float*)d_in[7];
    const float* eps_q = (const float*)d_in[8];
    const float* eps_k = (const float*)d_in[9];
    float* out = (float*)d_out;

    char* ws = (char*)d_ws;
    float* qraw = (float*)ws;                                        // 1 MB
    float* kraw = (float*)(ws + (1u << 20));                         // 1 MB
    float* mrow = kraw;       // 64 KB, overlays kraw AFTER frn_mish consumed it
    float* nu2  = (float*)(ws + (2u << 20));                         // 512 B
    unsigned short* qb = (unsigned short*)(ws + (2u << 20) + 4096);  // 512 KB
    unsigned short* kb = qb + (size_t)NB * NN * C16;                 // 512 KB
    unsigned short* vb = kb + (size_t)NB * NN * C16;                 // 8 MB
    unsigned short* xT = vb + (size_t)NB * CC * NN;                  // 8 MB
    unsigned short* wvb = xT + (size_t)NB * NN * CC;                 // 128 KB
    unsigned short* wqkb = wvb + (size_t)CC * CC;                    // 48 KB

    cast_x_kernel<<<dim3(64, 4, NB), dim3(256), 0, stream>>>(x, xT);
    cast_wv_kernel<<<dim3(64), dim3(256), 0, stream>>>(wv, wvb);
    cast_wqk_kernel<<<dim3(96), dim3(256), 0, stream>>>(wq, wk, wqkb);
    conv_qk_mfma<<<dim3(64, NB), dim3(256), 0, stream>>>(xT, wqkb, bq, bk, qraw, kraw);
    frn_stats_kernel<<<dim3(128), dim3(256), 0, stream>>>(qraw, kraw, nu2);
    frn_mish_kernel<<<dim3(128), dim3(256), 0, stream>>>(qraw, kraw, nu2, eps_q, eps_k, qb, kb);
    conv_v_mfma<<<dim3(64, NB, 2), dim3(256), 0, stream>>>(xT, wvb, bv, vb);
    row_max_kernel<<<dim3(64, NB), dim3(256), 0, stream>>>(qb, kb, mrow);
    attn_kernel<<<dim3(512), dim3(256), 0, stream>>>(qb, kb, vb, mrow, x, gamma, out);
}

// Round 4
// 221.842 us; speedup vs baseline: 2.1547x; 1.5442x over previous
//
#include <hip/hip_runtime.h>
#include <stdint.h>

#define NB 4
#define CC 256
#define C16 16
#define HH 64
#define WW 64
#define NN 4096

typedef __attribute__((ext_vector_type(8))) short short8;
typedef __attribute__((ext_vector_type(4))) float floatx4;
typedef __attribute__((ext_vector_type(16))) float floatx16;

__device__ __forceinline__ unsigned short f2bf(float f) {
    union { float f; unsigned u; } v; v.f = f;
    unsigned r = v.u + 0x7fffu + ((v.u >> 16) & 1u);
    return (unsigned short)(r >> 16);
}

// ---------------- cast x -> xT bf16 [b][n][c] (LDS transpose) ----------------
__global__ __launch_bounds__(256) void cast_x_kernel(
        const float* __restrict__ x, unsigned short* __restrict__ xT) {
    __shared__ float tile[64][65];
    int nt = blockIdx.x, ct = blockIdx.y, b = blockIdx.z;
    int n0 = nt * 64, c0 = ct * 64;
    int ln = threadIdx.x & 63, grp = threadIdx.x >> 6;
    const float* xb = x + ((size_t)b * CC + c0) * NN + n0;
    for (int i = 0; i < 16; ++i) {
        int c = i * 4 + grp;
        tile[c][ln] = xb[(size_t)c * NN + ln];
    }
    __syncthreads();
    unsigned short* xtb = xT + ((size_t)b * NN + n0) * CC + c0;
    for (int i = 0; i < 16; ++i) {
        int n = i * 4 + grp;
        xtb[(size_t)n * CC + ln] = f2bf(tile[ln][n]);
    }
}

// ---------------- cast wv -> bf16 ----------------
__global__ __launch_bounds__(256) void cast_wv_kernel(
        const float* __restrict__ wv, unsigned short* __restrict__ wvb) {
    int idx = (blockIdx.x * 256 + threadIdx.x) * 4;
    float4 v = *(const float4*)(wv + idx);
    ushort4 o;
    o.x = f2bf(v.x); o.y = f2bf(v.y); o.z = f2bf(v.z); o.w = f2bf(v.w);
    *(ushort4*)(wvb + idx) = o;
}

// ---------------- cast wq/wk -> bf16 A-frag layout [tensor][tap][o][c] ----------------
__global__ __launch_bounds__(256) void cast_wqk_kernel(
        const float* __restrict__ wq, const float* __restrict__ wk,
        unsigned short* __restrict__ wqkb) {
    int idx = blockIdx.x * 256 + threadIdx.x;     // 0..24575
    int t = idx / 12288;
    int i = idx - t * 12288;
    int tap = i >> 12, o = (i >> 8) & 15, c = i & 255;
    const float* src = t ? wk : wq;
    wqkb[idx] = f2bf(src[o * 768 + c * 3 + tap]);
}

// ---------------- q conv (1x3) + k conv (3x1) via MFMA im2col ----------------
// 1 wave per block, 16 n per block; grid (256, NB).
__global__ __launch_bounds__(64) void conv_qk_mfma(
        const unsigned short* __restrict__ xT, const unsigned short* __restrict__ wqkb,
        const float* __restrict__ bq, const float* __restrict__ bk,
        float* __restrict__ qraw, float* __restrict__ kraw) {
    int b = blockIdx.y;
    int lane = threadIdx.x;
    int q16 = lane >> 4, c16 = lane & 15;
    int n = blockIdx.x * 16 + c16;     // global n within batch
    int h = n >> 6, w = n & 63;
    bool vm1 = (w != 0), vp1 = (w != 63);
    bool vm64 = (h != 0), vp64 = (h != 63);
    short8 zero8 = {0, 0, 0, 0, 0, 0, 0, 0};
    floatx4 accq = {0.f, 0.f, 0.f, 0.f}, acck = {0.f, 0.f, 0.f, 0.f};
    const unsigned short* xb = xT + (size_t)b * NN * CC;
    const unsigned short* wrow = wqkb + c16 * 256;   // A-row m = o = c16
    for (int kc = 0; kc < 8; ++kc) {
        int ko = kc * 32 + q16 * 8;
        short8 b0 = *(const short8*)(xb + (size_t)n * CC + ko);
        short8 bm1 = vm1 ? *(const short8*)(xb + (size_t)(n - 1) * CC + ko) : zero8;
        short8 bp1 = vp1 ? *(const short8*)(xb + (size_t)(n + 1) * CC + ko) : zero8;
        short8 bm64 = vm64 ? *(const short8*)(xb + (size_t)(n - 64) * CC + ko) : zero8;
        short8 bp64 = vp64 ? *(const short8*)(xb + (size_t)(n + 64) * CC + ko) : zero8;
        short8 aq0 = *(const short8*)(wrow + 0 * 4096 + ko);
        short8 aq1 = *(const short8*)(wrow + 1 * 4096 + ko);
        short8 aq2 = *(const short8*)(wrow + 2 * 4096 + ko);
        short8 ak0 = *(const short8*)(wrow + 12288 + 0 * 4096 + ko);
        short8 ak1 = *(const short8*)(wrow + 12288 + 1 * 4096 + ko);
        short8 ak2 = *(const short8*)(wrow + 12288 + 2 * 4096 + ko);
        accq = __builtin_amdgcn_mfma_f32_16x16x32_bf16(aq0, bm1, accq, 0, 0, 0);
        accq = __builtin_amdgcn_mfma_f32_16x16x32_bf16(aq1, b0, accq, 0, 0, 0);
        accq = __builtin_amdgcn_mfma_f32_16x16x32_bf16(aq2, bp1, accq, 0, 0, 0);
        acck = __builtin_amdgcn_mfma_f32_16x16x32_bf16(ak0, bm64, acck, 0, 0, 0);
        acck = __builtin_amdgcn_mfma_f32_16x16x32_bf16(ak1, b0, acck, 0, 0, 0);
        acck = __builtin_amdgcn_mfma_f32_16x16x32_bf16(ak2, bp64, acck, 0, 0, 0);
    }
#pragma unroll
    for (int r = 0; r < 4; ++r) {
        int o = q16 * 4 + r;
        qraw[(size_t)(b * C16 + o) * NN + n] = accq[r] + bq[o];
        kraw[(size_t)(b * C16 + o) * NN + n] = acck[r] + bk[o];
    }
}

// ---------------- FRN stats: nu2[b,o] = mean over N of raw^2 ----------------
__global__ __launch_bounds__(256) void frn_stats_kernel(
        const float* __restrict__ qraw, const float* __restrict__ kraw,
        float* __restrict__ nu2) {
    int blk = blockIdx.x;                 // 0..63 q, 64..127 k
    const float* src = (blk & 64) ? kraw : qraw;
    int bo = blk & 63;
    const floatx4* p = (const floatx4*)(src + (size_t)bo * NN);
    float s = 0.f;
    for (int i = 0; i < 4; ++i) {
        floatx4 v = p[threadIdx.x + 256 * i];
        s += v[0]*v[0] + v[1]*v[1] + v[2]*v[2] + v[3]*v[3];
    }
    for (int off = 1; off < 64; off <<= 1) s += __shfl_xor(s, off, 64);
    __shared__ float part[4];
    if ((threadIdx.x & 63) == 0) part[threadIdx.x >> 6] = s;
    __syncthreads();
    if (threadIdx.x == 0)
        nu2[blk] = (part[0] + part[1] + part[2] + part[3]) * (1.f / (float)NN);
}

// ---------------- FRN normalize + Mish, transpose-write bf16 [b][n][16] ----------------
__global__ __launch_bounds__(256) void frn_mish_kernel(
        const float* __restrict__ qraw, const float* __restrict__ kraw,
        const float* __restrict__ nu2, const float* __restrict__ eps_q,
        const float* __restrict__ eps_k, unsigned short* __restrict__ qb,
        unsigned short* __restrict__ kb) {
    int blk = blockIdx.x;
    int tensor = blk >> 6;
    int b = (blk >> 4) & 3;
    int ch = blk & 15;
    const float* raw = tensor ? kraw : qraw;
    const float* eps = tensor ? eps_k : eps_q;
    unsigned short* outp = tensor ? kb : qb;
    const float* nu = nu2 + tensor * 64 + b * C16;
    int n = ch * 256 + threadIdx.x;
    union { unsigned short s[16]; uint4 u[2]; } pk;
    for (int o = 0; o < C16; ++o) {
        float r = raw[(size_t)(b * C16 + o) * NN + n];
        float v = r * rsqrtf(nu[o] + fabsf(eps[o]));
        float sp = fmaxf(v, 0.f) + log1pf(expf(-fabsf(v)));   // stable softplus
        pk.s[o] = f2bf(v * tanhf(sp));
    }
    uint4* dst = (uint4*)(outp + (size_t)(b * NN + n) * C16);
    dst[0] = pk.u[0];
    dst[1] = pk.u[1];
}

// ---------------- v = 1x1 conv via MFMA, bf16 out [b][c][n] ----------------
__global__ __launch_bounds__(256) void conv_v_mfma(
        const unsigned short* __restrict__ xT, const unsigned short* __restrict__ wvb,
        const float* __restrict__ bv, unsigned short* __restrict__ vb) {
    int ntile = blockIdx.x, b = blockIdx.y, ch = blockIdx.z;   // ch: 0..3
    int tid = threadIdx.x;
    int wv_ = tid >> 6, lane = tid & 63;
    int q16 = lane >> 4, c16 = lane & 15;
    int n0 = ntile * 64;
    int cb = ch * 64 + wv_ * 16;
    floatx4 fzero = {0.f, 0.f, 0.f, 0.f};
    floatx4 acc[4];
    for (int nt = 0; nt < 4; ++nt) acc[nt] = fzero;
    const unsigned short* xb = xT + ((size_t)b * NN + n0) * CC;
    for (int kc = 0; kc < 8; ++kc) {
        int ko = kc * 32 + q16 * 8;
        short8 a0 = *(const short8*)(wvb + (size_t)(cb + c16) * CC + ko);
        short8 bf[4];
#pragma unroll
        for (int nt = 0; nt < 4; ++nt)
            bf[nt] = *(const short8*)(xb + (size_t)(nt * 16 + c16) * CC + ko);
#pragma unroll
        for (int nt = 0; nt < 4; ++nt)
            acc[nt] = __builtin_amdgcn_mfma_f32_16x16x32_bf16(a0, bf[nt], acc[nt], 0, 0, 0);
    }
#pragma unroll
    for (int nt = 0; nt < 4; ++nt)
        for (int r = 0; r < 4; ++r) {
            int c = cb + q16 * 4 + r;
            vb[(size_t)(b * CC + c) * NN + n0 + nt * 16 + c16] = f2bf(acc[nt][r] + bv[c]);
        }
}

// ---------------- row max of S via 32x32x16, k-split waves, partial over ks ----------------
__global__ __launch_bounds__(256) void row_max_kernel(
        const unsigned short* __restrict__ qb, const unsigned short* __restrict__ kb,
        float* __restrict__ mpart) {
    int jt = blockIdx.x, b = blockIdx.y, ks = blockIdx.z;
    int tid = threadIdx.x;
    int wv_ = __builtin_amdgcn_readfirstlane(tid >> 6);
    int lane = tid & 63;
    int l31 = lane & 31, lh = lane >> 5;
    int jbase = jt * 64;
    const unsigned short* qbb = qb + (size_t)b * NN * C16;
    const unsigned short* kbb = kb + (size_t)b * NN * C16;
    short8 qf0 = *(const short8*)(qbb + (size_t)(jbase + l31) * C16 + lh * 8);
    short8 qf1 = *(const short8*)(qbb + (size_t)(jbase + 32 + l31) * C16 + lh * 8);
    floatx16 z16 = {0,0,0,0,0,0,0,0,0,0,0,0,0,0,0,0};
    int kw = ks * 2048 + wv_ * 512;
    short8 ak = *(const short8*)(kbb + (size_t)(kw + l31) * C16 + lh * 8);
    float mx0 = -INFINITY, mx1 = -INFINITY;
    for (int step = 0; step < 16; ++step) {
        short8 akc = ak;
        int kn = kw + ((step + 1) & 15) * 32;
        ak = *(const short8*)(kbb + (size_t)(kn + l31) * C16 + lh * 8);
        floatx16 s0 = __builtin_amdgcn_mfma_f32_32x32x16_bf16(akc, qf0, z16, 0, 0, 0);
        floatx16 s1 = __builtin_amdgcn_mfma_f32_32x32x16_bf16(akc, qf1, z16, 0, 0, 0);
#pragma unroll
        for (int r = 0; r < 16; ++r) {
            mx0 = fmaxf(mx0, s0[r]);
            mx1 = fmaxf(mx1, s1[r]);
        }
    }
    mx0 = fmaxf(mx0, __shfl_xor(mx0, 32, 64));
    mx1 = fmaxf(mx1, __shfl_xor(mx1, 32, 64));
    __shared__ float mp[4][2][32];
    if (lh == 0) { mp[wv_][0][l31] = mx0; mp[wv_][1][l31] = mx1; }
    __syncthreads();
    if (tid < 64) {
        int jb = tid >> 5, j31 = tid & 31;
        float m = fmaxf(fmaxf(mp[0][jb][j31], mp[1][jb][j31]),
                        fmaxf(mp[2][jb][j31], mp[3][jb][j31]));
        mpart[((size_t)ks * NB + b) * NN + jbase + tid] = m;
    }
}

// P-block processing: exp, pack to bf16 (perm truncation), half-lane exchange, 4 PV MFMAs
__device__ __forceinline__ void pv_block(
        floatx16 sc, float mneg, bool hi,
        short8 vf00, short8 vf01, short8 vf10, short8 vf11,
        floatx16* acc0, floatx16* acc1, float* lsum) {
    unsigned pk[8];
    float ls = 0.f;
#pragma unroll
    for (int p = 0; p < 8; ++p) {
        float e0 = __expf(sc[2 * p] + mneg);
        float e1 = __expf(sc[2 * p + 1] + mneg);
        ls += e0 + e1;
        pk[p] = __builtin_amdgcn_perm(__float_as_uint(e1), __float_as_uint(e0), 0x07060302u);
    }
    *lsum += ls;
    unsigned xk[8];
#pragma unroll
    for (int p = 0; p < 8; ++p) xk[p] = (unsigned)__shfl_xor((int)pk[p], 32, 64);
    union { unsigned u[4]; short8 s; } A0, A1;
    A0.u[0] = hi ? xk[2] : pk[0]; A0.u[1] = hi ? xk[3] : pk[1];
    A0.u[2] = hi ? pk[2] : xk[0]; A0.u[3] = hi ? pk[3] : xk[1];
    A1.u[0] = hi ? xk[6] : pk[4]; A1.u[1] = hi ? xk[7] : pk[5];
    A1.u[2] = hi ? pk[6] : xk[4]; A1.u[3] = hi ? pk[7] : xk[5];
    *acc0 = __builtin_amdgcn_mfma_f32_32x32x16_bf16(A0.s, vf00, *acc0, 0, 0, 0);
    *acc0 = __builtin_amdgcn_mfma_f32_32x32x16_bf16(A1.s, vf01, *acc0, 0, 0, 0);
    *acc1 = __builtin_amdgcn_mfma_f32_32x32x16_bf16(A0.s, vf10, *acc1, 0, 0, 0);
    *acc1 = __builtin_amdgcn_mfma_f32_32x32x16_bf16(A1.s, vf11, *acc1, 0, 0, 0);
}

// ---------------- attention: barrier-free main loop, waves split K ----------------
// grid 1024: cs = id&3 (64-c slice), b = (id>>2)&3, jt = id>>4 (64-j tile).
// Wave w streams k in [1024w, 1024w+1024) in 32-k steps; P register-resident.
__global__ __launch_bounds__(256, 3) void attn_kernel(
        const unsigned short* __restrict__ qb, const unsigned short* __restrict__ kb,
        const unsigned short* __restrict__ vb, const float* __restrict__ mpart,
        const float* __restrict__ x, const float* __restrict__ gamma_p,
        float* __restrict__ out) {
    __shared__ float obuf[4][64][33];
    __shared__ float lpart[4][2][32];

    int tid = threadIdx.x;
    int wv_ = __builtin_amdgcn_readfirstlane(tid >> 6);
    int lane = tid & 63;
    int l31 = lane & 31, lh = lane >> 5;
    bool hi = (lh != 0);
    int id = blockIdx.x;
    int cs = id & 3, b = (id >> 2) & 3, jt = id >> 4;
    int jbase = jt * 64, cb = cs * 64;

    const unsigned short* qbb = qb + (size_t)b * NN * C16;
    const unsigned short* kbb = kb + (size_t)b * NN * C16;
    const unsigned short* vbb = vb + ((size_t)b * CC + cb) * NN;

    // loop-invariant Q B-frags and -rowmax
    short8 qf0 = *(const short8*)(qbb + (size_t)(jbase + l31) * C16 + lh * 8);
    short8 qf1 = *(const short8*)(qbb + (size_t)(jbase + 32 + l31) * C16 + lh * 8);
    const float* mp0 = mpart + (size_t)b * NN + jbase;
    const float* mp1 = mpart + ((size_t)NB + b) * NN + jbase;
    float mneg0 = -fmaxf(mp0[l31], mp1[l31]);
    float mneg1 = -fmaxf(mp0[32 + l31], mp1[32 + l31]);

    floatx16 z16 = {0,0,0,0,0,0,0,0,0,0,0,0,0,0,0,0};
    floatx16 acc00 = z16, acc01 = z16, acc10 = z16, acc11 = z16;
    float lsum0 = 0.f, lsum1 = 0.f;

    int kw = wv_ * 1024;
    short8 ak = *(const short8*)(kbb + (size_t)(kw + l31) * C16 + lh * 8);
    const unsigned short* vrow0 = vbb + (size_t)l31 * NN;
    const unsigned short* vrow1 = vbb + (size_t)(32 + l31) * NN;

#pragma unroll 1
    for (int step = 0; step < 32; ++step) {
        int kg = kw + step * 32;
        short8 vf00 = *(const short8*)(vrow0 + kg + lh * 8);
        short8 vf01 = *(const short8*)(vrow0 + kg + 16 + lh * 8);
        short8 vf10 = *(const short8*)(vrow1 + kg + lh * 8);
        short8 vf11 = *(const short8*)(vrow1 + kg + 16 + lh * 8);
        floatx16 sc0 = __builtin_amdgcn_mfma_f32_32x32x16_bf16(ak, qf0, z16, 0, 0, 0);
        floatx16 sc1 = __builtin_amdgcn_mfma_f32_32x32x16_bf16(ak, qf1, z16, 0, 0, 0);
        int kn = kw + ((step + 1) & 31) * 32;
        ak = *(const short8*)(kbb + (size_t)(kn + l31) * C16 + lh * 8);
        pv_block(sc0, mneg0, hi, vf00, vf01, vf10, vf11, &acc00, &acc01, &lsum0);
        pv_block(sc1, mneg1, hi, vf00, vf01, vf10, vf11, &acc10, &acc11, &lsum1);
    }

    // l: combine lane halves (disjoint kcol rows), publish per-wave partials
    lsum0 += __shfl_xor(lsum0, 32, 64);
    lsum1 += __shfl_xor(lsum1, 32, 64);
    if (lh == 0) { lpart[wv_][0][l31] = lsum0; lpart[wv_][1][l31] = lsum1; }

    // O reduction over waves, c-half at a time; C row = (r&3)+8*(r>>2)+4*lh
    int hofs = lh * 4;
#pragma unroll
    for (int r = 0; r < 16; ++r) {
        int row = (r & 3) + 8 * (r >> 2) + hofs;
        obuf[wv_][row][l31]      = acc00[r];
        obuf[wv_][32 + row][l31] = acc10[r];
    }
    __syncthreads();
    int jq = tid & 63, cq = (tid >> 6) * 8;
    float lj = lpart[0][jq >> 5][jq & 31] + lpart[1][jq >> 5][jq & 31] +
               lpart[2][jq >> 5][jq & 31] + lpart[3][jq >> 5][jq & 31];
    float gl = gamma_p[0] / lj;
    const float* xbb = x + (size_t)b * CC * NN;
    float* obb = out + (size_t)b * CC * NN;
#pragma unroll
    for (int i = 0; i < 8; ++i) {
        int c = cq + i;
        float val = obuf[0][jq][c] + obuf[1][jq][c] + obuf[2][jq][c] + obuf[3][jq][c];
        size_t oidx = (size_t)(cb + c) * NN + jbase + jq;
        obb[oidx] = fmaf(gl, val, xbb[oidx]);
    }
    __syncthreads();
#pragma unroll
    for (int r = 0; r < 16; ++r) {
        int row = (r & 3) + 8 * (r >> 2) + hofs;
        obuf[wv_][row][l31]      = acc01[r];
        obuf[wv_][32 + row][l31] = acc11[r];
    }
    __syncthreads();
#pragma unroll
    for (int i = 0; i < 8; ++i) {
        int c = cq + i;
        float val = obuf[0][jq][c] + obuf[1][jq][c] + obuf[2][jq][c] + obuf[3][jq][c];
        size_t oidx = (size_t)(cb + 32 + c) * NN + jbase + jq;
        obb[oidx] = fmaf(gl, val, xbb[oidx]);
    }
}

extern "C" void kernel_launch(void* const* d_in, const int* in_sizes, int n_in,
                              void* d_out, int out_size, void* d_ws, size_t ws_size,
                              hipStream_t stream) {
    const float* x     = (const float*)d_in[0];
    const float* wq    = (const float*)d_in[1];
    const float* bq    = (const float*)d_in[2];
    const float* wk    = (const float*)d_in[3];
    const float* bk    = (const float*)d_in[4];
    const float* wv    = (const float*)d_in[5];
    const float* bv    = (const float*)d_in[6];
    const float* gamma = (const float*)d_in[7];
    const float* eps_q = (const float*)d_in[8];
    const float* eps_k = (const float*)d_in[9];
    float* out = (float*)d_out;

    char* ws = (char*)d_ws;
    float* qraw = (float*)ws;                                        // 1 MB
    float* kraw = (float*)(ws + (1u << 20));                         // 1 MB
    float* nu2  = (float*)(ws + (2u << 20));                         // 512 B
    unsigned short* qb = (unsigned short*)(ws + (2u << 20) + 4096);  // 512 KB
    unsigned short* kb = qb + (size_t)NB * NN * C16;                 // 512 KB
    unsigned short* vb = kb + (size_t)NB * NN * C16;                 // 8 MB
    unsigned short* xT = vb + (size_t)NB * CC * NN;                  // 8 MB
    unsigned short* wvb = xT + (size_t)NB * NN * CC;                 // 128 KB
    unsigned short* wqkb = wvb + (size_t)CC * CC;                    // 48 KB
    float* mpart = (float*)(wqkb + 24576);                           // 128 KB

    cast_x_kernel<<<dim3(64, 4, NB), dim3(256), 0, stream>>>(x, xT);
    cast_wv_kernel<<<dim3(64), dim3(256), 0, stream>>>(wv, wvb);
    cast_wqk_kernel<<<dim3(96), dim3(256), 0, stream>>>(wq, wk, wqkb);
    conv_qk_mfma<<<dim3(256, NB), dim3(64), 0, stream>>>(xT, wqkb, bq, bk, qraw, kraw);
    frn_stats_kernel<<<dim3(128), dim3(256), 0, stream>>>(qraw, kraw, nu2);
    frn_mish_kernel<<<dim3(128), dim3(256), 0, stream>>>(qraw, kraw, nu2, eps_q, eps_k, qb, kb);
    conv_v_mfma<<<dim3(64, NB, 4), dim3(256), 0, stream>>>(xT, wvb, bv, vb);
    row_max_kernel<<<dim3(64, NB, 2), dim3(256), 0, stream>>>(qb, kb, mpart);
    attn_kernel<<<dim3(1024), dim3(256), 0, stream>>>(qb, kb, vb, mpart, x, gamma, out);
}

// Round 5
// 210.617 us; speedup vs baseline: 2.2696x; 1.0533x over previous
//
#include <hip/hip_runtime.h>
#include <stdint.h>

#define NB 4
#define CC 256
#define C16 16
#define HH 64
#define WW 64
#define NN 4096

typedef __attribute__((ext_vector_type(8))) short short8;
typedef __attribute__((ext_vector_type(4))) float floatx4;
typedef __attribute__((ext_vector_type(16))) float floatx16;

__device__ __forceinline__ unsigned short f2bf(float f) {
    union { float f; unsigned u; } v; v.f = f;
    unsigned r = v.u + 0x7fffu + ((v.u >> 16) & 1u);
    return (unsigned short)(r >> 16);
}

// ---------------- cast x -> xT bf16 [b][n][c] (LDS transpose) ----------------
__global__ __launch_bounds__(256) void cast_x_kernel(
        const float* __restrict__ x, unsigned short* __restrict__ xT) {
    __shared__ float tile[64][65];
    int nt = blockIdx.x, ct = blockIdx.y, b = blockIdx.z;
    int n0 = nt * 64, c0 = ct * 64;
    int ln = threadIdx.x & 63, grp = threadIdx.x >> 6;
    const float* xb = x + ((size_t)b * CC + c0) * NN + n0;
    for (int i = 0; i < 16; ++i) {
        int c = i * 4 + grp;
        tile[c][ln] = xb[(size_t)c * NN + ln];
    }
    __syncthreads();
    unsigned short* xtb = xT + ((size_t)b * NN + n0) * CC + c0;
    for (int i = 0; i < 16; ++i) {
        int n = i * 4 + grp;
        xtb[(size_t)n * CC + ln] = f2bf(tile[ln][n]);
    }
}

// ---------------- cast wv + wq/wk -> bf16 (merged) ----------------
// wvb: straight cast of 65536 elems. wqkb layout [t][tap][o][c].
__global__ __launch_bounds__(256) void cast_w_kernel(
        const float* __restrict__ wv, const float* __restrict__ wq,
        const float* __restrict__ wk, unsigned short* __restrict__ wvb,
        unsigned short* __restrict__ wqkb) {
    int idx = blockIdx.x * 256 + threadIdx.x;
    if (idx < 16384) {
        float4 v = *(const float4*)(wv + idx * 4);
        ushort4 o;
        o.x = f2bf(v.x); o.y = f2bf(v.y); o.z = f2bf(v.z); o.w = f2bf(v.w);
        *(ushort4*)(wvb + idx * 4) = o;
    } else if (idx < 16384 + 6144) {
        int base = (idx - 16384) * 4;
#pragma unroll
        for (int u = 0; u < 4; ++u) {
            int e = base + u;
            int t = e / 12288;
            int i = e - t * 12288;
            int tap = i >> 12, o = (i >> 8) & 15, c = i & 255;
            const float* src = t ? wk : wq;
            wqkb[e] = f2bf(src[o * 768 + c * 3 + tap]);
        }
    }
}

// ---------------- q conv (1x3) + k conv (3x1) via MFMA im2col ----------------
__global__ __launch_bounds__(64) void conv_qk_mfma(
        const unsigned short* __restrict__ xT, const unsigned short* __restrict__ wqkb,
        const float* __restrict__ bq, const float* __restrict__ bk,
        float* __restrict__ qraw, float* __restrict__ kraw) {
    int b = blockIdx.y;
    int lane = threadIdx.x;
    int q16 = lane >> 4, c16 = lane & 15;
    int n = blockIdx.x * 16 + c16;     // global n within batch
    int h = n >> 6, w = n & 63;
    bool vm1 = (w != 0), vp1 = (w != 63);
    bool vm64 = (h != 0), vp64 = (h != 63);
    short8 zero8 = {0, 0, 0, 0, 0, 0, 0, 0};
    floatx4 accq = {0.f, 0.f, 0.f, 0.f}, acck = {0.f, 0.f, 0.f, 0.f};
    const unsigned short* xb = xT + (size_t)b * NN * CC;
    const unsigned short* wrow = wqkb + c16 * 256;   // A-row m = o = c16
    for (int kc = 0; kc < 8; ++kc) {
        int ko = kc * 32 + q16 * 8;
        short8 b0 = *(const short8*)(xb + (size_t)n * CC + ko);
        short8 bm1 = vm1 ? *(const short8*)(xb + (size_t)(n - 1) * CC + ko) : zero8;
        short8 bp1 = vp1 ? *(const short8*)(xb + (size_t)(n + 1) * CC + ko) : zero8;
        short8 bm64 = vm64 ? *(const short8*)(xb + (size_t)(n - 64) * CC + ko) : zero8;
        short8 bp64 = vp64 ? *(const short8*)(xb + (size_t)(n + 64) * CC + ko) : zero8;
        short8 aq0 = *(const short8*)(wrow + 0 * 4096 + ko);
        short8 aq1 = *(const short8*)(wrow + 1 * 4096 + ko);
        short8 aq2 = *(const short8*)(wrow + 2 * 4096 + ko);
        short8 ak0 = *(const short8*)(wrow + 12288 + 0 * 4096 + ko);
        short8 ak1 = *(const short8*)(wrow + 12288 + 1 * 4096 + ko);
        short8 ak2 = *(const short8*)(wrow + 12288 + 2 * 4096 + ko);
        accq = __builtin_amdgcn_mfma_f32_16x16x32_bf16(aq0, bm1, accq, 0, 0, 0);
        accq = __builtin_amdgcn_mfma_f32_16x16x32_bf16(aq1, b0, accq, 0, 0, 0);
        accq = __builtin_amdgcn_mfma_f32_16x16x32_bf16(aq2, bp1, accq, 0, 0, 0);
        acck = __builtin_amdgcn_mfma_f32_16x16x32_bf16(ak0, bm64, acck, 0, 0, 0);
        acck = __builtin_amdgcn_mfma_f32_16x16x32_bf16(ak1, b0, acck, 0, 0, 0);
        acck = __builtin_amdgcn_mfma_f32_16x16x32_bf16(ak2, bp64, acck, 0, 0, 0);
    }
#pragma unroll
    for (int r = 0; r < 4; ++r) {
        int o = q16 * 4 + r;
        qraw[(size_t)(b * C16 + o) * NN + n] = accq[r] + bq[o];
        kraw[(size_t)(b * C16 + o) * NN + n] = acck[r] + bk[o];
    }
}

// ---------------- FRN stats: nu2[b,o] = mean over N of raw^2 ----------------
__global__ __launch_bounds__(256) void frn_stats_kernel(
        const float* __restrict__ qraw, const float* __restrict__ kraw,
        float* __restrict__ nu2) {
    int blk = blockIdx.x;                 // 0..63 q, 64..127 k
    const float* src = (blk & 64) ? kraw : qraw;
    int bo = blk & 63;
    const floatx4* p = (const floatx4*)(src + (size_t)bo * NN);
    float s = 0.f;
    for (int i = 0; i < 4; ++i) {
        floatx4 v = p[threadIdx.x + 256 * i];
        s += v[0]*v[0] + v[1]*v[1] + v[2]*v[2] + v[3]*v[3];
    }
    for (int off = 1; off < 64; off <<= 1) s += __shfl_xor(s, off, 64);
    __shared__ float part[4];
    if ((threadIdx.x & 63) == 0) part[threadIdx.x >> 6] = s;
    __syncthreads();
    if (threadIdx.x == 0)
        nu2[blk] = (part[0] + part[1] + part[2] + part[3]) * (1.f / (float)NN);
}

// ---------------- FRN normalize + Mish, transpose-write bf16 [b][n][16] ----------------
__global__ __launch_bounds__(256) void frn_mish_kernel(
        const float* __restrict__ qraw, const float* __restrict__ kraw,
        const float* __restrict__ nu2, const float* __restrict__ eps_q,
        const float* __restrict__ eps_k, unsigned short* __restrict__ qb,
        unsigned short* __restrict__ kb) {
    int blk = blockIdx.x;
    int tensor = blk >> 6;
    int b = (blk >> 4) & 3;
    int ch = blk & 15;
    const float* raw = tensor ? kraw : qraw;
    const float* eps = tensor ? eps_k : eps_q;
    unsigned short* outp = tensor ? kb : qb;
    const float* nu = nu2 + tensor * 64 + b * C16;
    int n = ch * 256 + threadIdx.x;
    union { unsigned short s[16]; uint4 u[2]; } pk;
    for (int o = 0; o < C16; ++o) {
        float r = raw[(size_t)(b * C16 + o) * NN + n];
        float v = r * rsqrtf(nu[o] + fabsf(eps[o]));
        float sp = fmaxf(v, 0.f) + log1pf(expf(-fabsf(v)));   // stable softplus
        pk.s[o] = f2bf(v * tanhf(sp));
    }
    uint4* dst = (uint4*)(outp + (size_t)(b * NN + n) * C16);
    dst[0] = pk.u[0];
    dst[1] = pk.u[1];
}

// ---------------- v = 1x1 conv via MFMA, bf16 out [b][c][n] ----------------
__global__ __launch_bounds__(256) void conv_v_mfma(
        const unsigned short* __restrict__ xT, const unsigned short* __restrict__ wvb,
        const float* __restrict__ bv, unsigned short* __restrict__ vb) {
    int ntile = blockIdx.x, b = blockIdx.y, ch = blockIdx.z;   // ch: 0..3
    int tid = threadIdx.x;
    int wv_ = tid >> 6, lane = tid & 63;
    int q16 = lane >> 4, c16 = lane & 15;
    int n0 = ntile * 64;
    int cb = ch * 64 + wv_ * 16;
    floatx4 fzero = {0.f, 0.f, 0.f, 0.f};
    floatx4 acc[4];
    for (int nt = 0; nt < 4; ++nt) acc[nt] = fzero;
    const unsigned short* xb = xT + ((size_t)b * NN + n0) * CC;
    for (int kc = 0; kc < 8; ++kc) {
        int ko = kc * 32 + q16 * 8;
        short8 a0 = *(const short8*)(wvb + (size_t)(cb + c16) * CC + ko);
        short8 bf[4];
#pragma unroll
        for (int nt = 0; nt < 4; ++nt)
            bf[nt] = *(const short8*)(xb + (size_t)(nt * 16 + c16) * CC + ko);
#pragma unroll
        for (int nt = 0; nt < 4; ++nt)
            acc[nt] = __builtin_amdgcn_mfma_f32_16x16x32_bf16(a0, bf[nt], acc[nt], 0, 0, 0);
    }
#pragma unroll
    for (int nt = 0; nt < 4; ++nt)
        for (int r = 0; r < 4; ++r) {
            int c = cb + q16 * 4 + r;
            vb[(size_t)(b * CC + c) * NN + n0 + nt * 16 + c16] = f2bf(acc[nt][r] + bv[c]);
        }
}

// P-block: exp, pack bf16 (perm truncation), half-lane exchange -> A-frags, PV over 4 c-groups
__device__ __forceinline__ void pv_block(
        floatx16 sc, float mneg, bool hi, const short8* vf /*[4][2] flattened*/,
        floatx16* acc /*[4]*/, float* lsum) {
    unsigned pk[8];
    float ls = 0.f;
#pragma unroll
    for (int p = 0; p < 8; ++p) {
        float e0 = __expf(sc[2 * p] + mneg);
        float e1 = __expf(sc[2 * p + 1] + mneg);
        ls += e0 + e1;
        pk[p] = __builtin_amdgcn_perm(__float_as_uint(e1), __float_as_uint(e0), 0x07060302u);
    }
    *lsum += ls;
    unsigned xk[8];
#pragma unroll
    for (int p = 0; p < 8; ++p) xk[p] = (unsigned)__shfl_xor((int)pk[p], 32, 64);
    union { unsigned u[4]; short8 s; } A0, A1;
    A0.u[0] = hi ? xk[2] : pk[0]; A0.u[1] = hi ? xk[3] : pk[1];
    A0.u[2] = hi ? pk[2] : xk[0]; A0.u[3] = hi ? pk[3] : xk[1];
    A1.u[0] = hi ? xk[6] : pk[4]; A1.u[1] = hi ? xk[7] : pk[5];
    A1.u[2] = hi ? pk[6] : xk[4]; A1.u[3] = hi ? pk[7] : xk[5];
#pragma unroll
    for (int cg = 0; cg < 4; ++cg) {
        acc[cg] = __builtin_amdgcn_mfma_f32_32x32x16_bf16(A0.s, vf[cg * 2 + 0], acc[cg], 0, 0, 0);
        acc[cg] = __builtin_amdgcn_mfma_f32_32x32x16_bf16(A1.s, vf[cg * 2 + 1], acc[cg], 0, 0, 0);
    }
}

// ---------------- attention: barrier-free main loop, in-kernel max pre-pass ----------------
// grid 512: cs = id&1 (128-c slice), b = (id>>1)&3, jt = id>>3 (64-j tile).
// id&7 <-> (cs,b): each XCD owns one (cs,b) -> V slice (1 MB) + K + Q L2-resident.
// Block 256 = 4 waves, wave w streams k in [1024w, 1024w+1024) in 32-k steps.
__global__ __launch_bounds__(256, 2) void attn_kernel(
        const unsigned short* __restrict__ qb, const unsigned short* __restrict__ kb,
        const unsigned short* __restrict__ vb, const float* __restrict__ x,
        const float* __restrict__ gamma_p, float* __restrict__ out) {
    __shared__ float mp[4][2][32];
    __shared__ float lpart[4][2][32];
    __shared__ float obuf[4][64][33];

    int tid = threadIdx.x;
    int wv_ = __builtin_amdgcn_readfirstlane(tid >> 6);
    int lane = tid & 63;
    int l31 = lane & 31, lh = lane >> 5;
    bool hi = (lh != 0);
    int id = blockIdx.x;
    int cs = id & 1, b = (id >> 1) & 3, jt = id >> 3;
    int jbase = jt * 64, cb = cs * 128;

    const unsigned short* qbb = qb + (size_t)b * NN * C16;
    const unsigned short* kbb = kb + (size_t)b * NN * C16;
    const unsigned short* vbb = vb + ((size_t)b * CC + cb) * NN;

    // loop-invariant Q B-frags (B[k=d][n=j])
    short8 qf0 = *(const short8*)(qbb + (size_t)(jbase + l31) * C16 + lh * 8);
    short8 qf1 = *(const short8*)(qbb + (size_t)(jbase + 32 + l31) * C16 + lh * 8);

    floatx16 z16 = {0,0,0,0,0,0,0,0,0,0,0,0,0,0,0,0};
    int kw = wv_ * 1024;

    // ---- pre-pass: row max over this wave's k-range (2 frags in flight) ----
    float mx0 = -INFINITY, mx1 = -INFINITY;
    {
        short8 a0 = *(const short8*)(kbb + (size_t)(kw + l31) * C16 + lh * 8);
        short8 a1 = *(const short8*)(kbb + (size_t)(kw + 32 + l31) * C16 + lh * 8);
#pragma unroll 1
        for (int s = 0; s < 32; s += 2) {
            floatx16 s0 = __builtin_amdgcn_mfma_f32_32x32x16_bf16(a0, qf0, z16, 0, 0, 0);
            floatx16 s1 = __builtin_amdgcn_mfma_f32_32x32x16_bf16(a0, qf1, z16, 0, 0, 0);
            a0 = *(const short8*)(kbb + (size_t)(kw + ((s + 2) & 31) * 32 + l31) * C16 + lh * 8);
            floatx16 s2 = __builtin_amdgcn_mfma_f32_32x32x16_bf16(a1, qf0, z16, 0, 0, 0);
            floatx16 s3 = __builtin_amdgcn_mfma_f32_32x32x16_bf16(a1, qf1, z16, 0, 0, 0);
            a1 = *(const short8*)(kbb + (size_t)(kw + ((s + 3) & 31) * 32 + l31) * C16 + lh * 8);
#pragma unroll
            for (int r = 0; r < 16; ++r) {
                mx0 = fmaxf(mx0, fmaxf(s0[r], s2[r]));
                mx1 = fmaxf(mx1, fmaxf(s1[r], s3[r]));
            }
        }
    }
    mx0 = fmaxf(mx0, __shfl_xor(mx0, 32, 64));
    mx1 = fmaxf(mx1, __shfl_xor(mx1, 32, 64));
    if (lh == 0) { mp[wv_][0][l31] = mx0; mp[wv_][1][l31] = mx1; }
    __syncthreads();
    float mneg0 = -fmaxf(fmaxf(mp[0][0][l31], mp[1][0][l31]),
                         fmaxf(mp[2][0][l31], mp[3][0][l31]));
    float mneg1 = -fmaxf(fmaxf(mp[0][1][l31], mp[1][1][l31]),
                         fmaxf(mp[2][1][l31], mp[3][1][l31]));

    // ---- main loop ----
    floatx16 acc0[4], acc1[4];
#pragma unroll
    for (int cg = 0; cg < 4; ++cg) { acc0[cg] = z16; acc1[cg] = z16; }
    float lsum0 = 0.f, lsum1 = 0.f;

    short8 ak = *(const short8*)(kbb + (size_t)(kw + l31) * C16 + lh * 8);
#pragma unroll 1
    for (int step = 0; step < 32; ++step) {
        int kg = kw + step * 32;
        short8 vf[8];
#pragma unroll
        for (int cg = 0; cg < 4; ++cg) {
            vf[cg * 2 + 0] = *(const short8*)(vbb + (size_t)(cg * 32 + l31) * NN + kg + lh * 8);
            vf[cg * 2 + 1] = *(const short8*)(vbb + (size_t)(cg * 32 + l31) * NN + kg + 16 + lh * 8);
        }
        floatx16 sc0 = __builtin_amdgcn_mfma_f32_32x32x16_bf16(ak, qf0, z16, 0, 0, 0);
        floatx16 sc1 = __builtin_amdgcn_mfma_f32_32x32x16_bf16(ak, qf1, z16, 0, 0, 0);
        ak = *(const short8*)(kbb + (size_t)(kw + ((step + 1) & 31) * 32 + l31) * C16 + lh * 8);
        pv_block(sc0, mneg0, hi, vf, acc0, &lsum0);
        pv_block(sc1, mneg1, hi, vf, acc1, &lsum1);
    }

    // l partials: combine lane halves (disjoint kcols), publish per wave
    lsum0 += __shfl_xor(lsum0, 32, 64);
    lsum1 += __shfl_xor(lsum1, 32, 64);
    if (lh == 0) { lpart[wv_][0][l31] = lsum0; lpart[wv_][1][l31] = lsum1; }
    __syncthreads();

    int jq = tid & 63;
    float lj = lpart[0][jq >> 5][jq & 31] + lpart[1][jq >> 5][jq & 31] +
               lpart[2][jq >> 5][jq & 31] + lpart[3][jq >> 5][jq & 31];
    float gl = gamma_p[0] / lj;
    const float* xbb = x + (size_t)b * CC * NN;
    float* obb = out + (size_t)b * CC * NN;
    int hofs = lh * 4;
    int cq = (tid >> 6) * 8;
    // O reduction over waves, one 32-c group at a time
#pragma unroll
    for (int cg = 0; cg < 4; ++cg) {
        __syncthreads();
#pragma unroll
        for (int r = 0; r < 16; ++r) {
            int row = (r & 3) + 8 * (r >> 2) + hofs;
            obuf[wv_][row][l31]      = acc0[cg][r];
            obuf[wv_][32 + row][l31] = acc1[cg][r];
        }
        __syncthreads();
#pragma unroll
        for (int i = 0; i < 8; ++i) {
            int cl = cq + i;
            float val = obuf[0][jq][cl] + obuf[1][jq][cl] + obuf[2][jq][cl] + obuf[3][jq][cl];
            size_t oidx = (size_t)(cb + cg * 32 + cl) * NN + jbase + jq;
            obb[oidx] = fmaf(gl, val, xbb[oidx]);
        }
    }
}

extern "C" void kernel_launch(void* const* d_in, const int* in_sizes, int n_in,
                              void* d_out, int out_size, void* d_ws, size_t ws_size,
                              hipStream_t stream) {
    const float* x     = (const float*)d_in[0];
    const float* wq    = (const float*)d_in[1];
    const float* bq    = (const float*)d_in[2];
    const float* wk    = (const float*)d_in[3];
    const float* bk    = (const float*)d_in[4];
    const float* wv    = (const float*)d_in[5];
    const float* bv    = (const float*)d_in[6];
    const float* gamma = (const float*)d_in[7];
    const float* eps_q = (const float*)d_in[8];
    const float* eps_k = (const float*)d_in[9];
    float* out = (float*)d_out;

    char* ws = (char*)d_ws;
    float* qraw = (float*)ws;                                        // 1 MB
    float* kraw = (float*)(ws + (1u << 20));                         // 1 MB
    float* nu2  = (float*)(ws + (2u << 20));                         // 512 B
    unsigned short* qb = (unsigned short*)(ws + (2u << 20) + 4096);  // 512 KB
    unsigned short* kb = qb + (size_t)NB * NN * C16;                 // 512 KB
    unsigned short* vb = kb + (size_t)NB * NN * C16;                 // 8 MB
    unsigned short* xT = vb + (size_t)NB * CC * NN;                  // 8 MB
    unsigned short* wvb = xT + (size_t)NB * NN * CC;                 // 128 KB
    unsigned short* wqkb = wvb + (size_t)CC * CC;                    // 48 KB

    cast_x_kernel<<<dim3(64, 4, NB), dim3(256), 0, stream>>>(x, xT);
    cast_w_kernel<<<dim3(88), dim3(256), 0, stream>>>(wv, wq, wk, wvb, wqkb);
    conv_qk_mfma<<<dim3(256, NB), dim3(64), 0, stream>>>(xT, wqkb, bq, bk, qraw, kraw);
    frn_stats_kernel<<<dim3(128), dim3(256), 0, stream>>>(qraw, kraw, nu2);
    frn_mish_kernel<<<dim3(128), dim3(256), 0, stream>>>(qraw, kraw, nu2, eps_q, eps_k, qb, kb);
    conv_v_mfma<<<dim3(64, NB, 4), dim3(256), 0, stream>>>(xT, wvb, bv, vb);
    attn_kernel<<<dim3(512), dim3(256), 0, stream>>>(qb, kb, vb, x, gamma, out);
}